// Round 7
// baseline (2046.810 us; speedup 1.0000x reference)
//
#include <hip/hip_runtime.h>
#include <math.h>

// ---------------- problem constants ----------------
#define BATCH   2
#define CIN     1024
#define COUT    1024
#define HH      50
#define WW      84
#define HWX     4200          // 50*84
#define NA      15
#define NSC     63000         // HWX*NA
#define TOPN    2000
#define POSTN   300
#define CAP2    4096          // candidate capacity (24-bit refined cut)
#define CLS_OFF   0           // floats into d_out
#define BBOX_OFF  252000      // 2*30*4200
#define ROIS_OFF  756000      // + 2*60*4200
#define PROBS_OFF 759000      // + 600*5

// Winograd F(4x4,3x3) geometry (per image)
#define TPI 273               // tiles per image (13*21)
#define USTR 274              // padded t-stride (even -> 16B-aligned rows)

__constant__ double ANCH[NA][4] = {
  {-15.0,  -4.0,  30.0, 19.0},
  {-38.0, -16.0,  53.0, 31.0},
  {-84.0, -40.0,  99.0, 55.0},
  {-176.0,-88.0, 191.0,103.0},
  {-360.0,-184.0,375.0,199.0},
  {-8.0,  -8.0,  23.0, 23.0},
  {-24.0, -24.0, 39.0, 39.0},
  {-56.0, -56.0, 71.0, 71.0},
  {-120.0,-120.0,135.0,135.0},
  {-248.0,-248.0,263.0,263.0},
  {-3.0, -14.0, 18.0, 29.0},
  {-14.0, -36.0, 29.0, 51.0},
  {-36.0, -80.0, 51.0, 95.0},
  {-80.0,-168.0, 95.0,183.0},
  {-168.0,-344.0,183.0,359.0}
};

// B^T rows (6x6) for F(4,3)
__constant__ double BTd[6][6] = {
  {4.0,  0.0, -5.0,  0.0, 1.0, 0.0},
  {0.0, -4.0, -4.0,  1.0, 1.0, 0.0},
  {0.0,  4.0, -4.0, -1.0, 1.0, 0.0},
  {0.0, -2.0, -1.0,  2.0, 1.0, 0.0},
  {0.0,  2.0, -1.0, -2.0, 1.0, 0.0},
  {0.0,  4.0,  0.0, -5.0, 0.0, 1.0}
};
// A^T (4x6)
__constant__ double ATd[4][6] = {
  {1.0, 1.0,  1.0, 1.0,  1.0, 0.0},
  {0.0, 1.0, -1.0, 2.0, -2.0, 0.0},
  {0.0, 1.0,  1.0, 4.0,  4.0, 0.0},
  {0.0, 1.0, -1.0, 8.0, -8.0, 1.0}
};

#define BBOX_CLIP 4.1351665567423560     // log(1000/16) in double

// ---------------- workspace float-slot offsets ----------------
// Dense [b][m][co] h64 keeps total at 146.42 MB < R3-proven 148.06 MB.
#define WS_WT     0            // 98,304 f
#define WS_U      98304        // U6: 6*1024*274 f64 = 3,366,912 f
#define WS_V      3465216      // V6: 6*1048576 f64 = 12,582,912 f
#define WS_C      16048128     // C6: 6*273*1024 f64 = 3,354,624 f
#define WS_H64    19402752     // h64: 2*4200*1024 f64 = 17,203,200 f
// end = 36,605,952 f = 146.42 MB
// ---- overlays ----
// h f32 (8,601,600 f) overlays V (dead after last wgemm)
#define OV_H      WS_V
// scores/topk/boxes/mask overlay C (dead after last otrans)
#define OV_SC     (WS_C + 0)        // scores 126,000 f
#define OV_TIDX   (WS_C + 126000)   // 4,000 u32
#define OV_TSC    (WS_C + 130000)   // 4,000 f
#define OV_BOX    (WS_C + 134000)   // 16,000 f64 (32,000 slots)
#define OV_MASK   (WS_C + 166000)   // 128,000 u64 (256,000 slots)

typedef double dx4 __attribute__((ext_vector_type(4)));

__device__ __forceinline__ void gload16(const void* gptr, void* lptr) {
  __builtin_amdgcn_global_load_lds(
      (const __attribute__((address_space(1))) unsigned int*)gptr,
      (__attribute__((address_space(3))) unsigned int*)lptr, 16, 0, 0);
}
#define MFMA64(a, b, c) __builtin_amdgcn_mfma_f64_16x16x4f64(a, b, c, 0, 0, 0)

// ================= W1: input transform, ONE B^T-row r per launch =================
__launch_bounds__(256)
__global__ void itrans_k(const float* __restrict__ x, double* __restrict__ U,
                         int b, int r) {
  __shared__ float XT[8][6][84];     // 16 KB
  const int bx = blockIdx.x;         // 0..1663 = ty*128 + cg
  const int cg  = bx & 127;
  const int ty  = bx >> 7;
  const int ci0 = cg * 8;
  for (int e = threadIdx.x; e < 4032; e += 256) {
    int ci = e / 504, rem = e % 504;
    int ry = rem / 84, xx = rem % 84;
    int y = ty*4 - 1 + ry;
    float v = 0.f;
    if (y >= 0 && y < HH) v = x[((size_t)(b*CIN + ci0 + ci)*HH + y)*WW + xx];
    XT[ci][ry][xx] = v;
  }
  __syncthreads();
  const int tid = threadIdx.x;
  if (tid < 168) {
    const int ci = tid / 21, tx = tid % 21;
    const double c0 = BTd[r][0], c1 = BTd[r][1], c2 = BTd[r][2];
    const double c3 = BTd[r][3], c4 = BTd[r][4], c5 = BTd[r][5];
    double tt[6];
#pragma unroll
    for (int j = 0; j < 6; ++j) {
      int col = tx*4 - 1 + j;
      double v = 0.0;
      if (col >= 0 && col < WW) {
        v = c0*(double)XT[ci][0][col] + c1*(double)XT[ci][1][col]
          + c2*(double)XT[ci][2][col] + c3*(double)XT[ci][3][col]
          + c4*(double)XT[ci][4][col] + c5*(double)XT[ci][5][col];
      }
      tt[j] = v;
    }
    const int t = ty*21 + tx;
#pragma unroll
    for (int c = 0; c < 6; ++c) {
      double u = BTd[c][0]*tt[0] + BTd[c][1]*tt[1] + BTd[c][2]*tt[2]
               + BTd[c][3]*tt[3] + BTd[c][4]*tt[4] + BTd[c][5]*tt[5];
      U[(size_t)(c*1024 + ci0 + ci)*USTR + t] = u;
    }
  }
}

// ================= W2: weight transform V[c][ci][co] for row r (b-independent) =================
#define GR0(a,b,c) (0.25*(a))
#define GR1(a,b,c) (-((a)+(b)+(c))*(1.0/6.0))
#define GR2(a,b,c) ((-(a)+(b)-(c))*(1.0/6.0))
#define GR3(a,b,c) (((a)+2.0*(b)+4.0*(c))*(1.0/24.0))
#define GR4(a,b,c) (((a)-2.0*(b)+4.0*(c))*(1.0/24.0))
#define GR5(a,b,c) ((c))
__launch_bounds__(256)
__global__ void wtrans_k(const float* __restrict__ conv_w, double* __restrict__ V,
                         int r) {
  const int g = blockIdx.x*256 + threadIdx.x;    // 1,048,576 threads
  const int co = g & 1023, ci = g >> 10;
  const float* gp = conv_w + (size_t)(co*1024 + ci)*9;
  double g00 = (double)gp[0], g01 = (double)gp[1], g02 = (double)gp[2];
  double g10 = (double)gp[3], g11 = (double)gp[4], g12 = (double)gp[5];
  double g20 = (double)gp[6], g21 = (double)gp[7], g22 = (double)gp[8];
  double p0, p1, p2;   // row r of G*g
  switch (r) {
    case 0: p0=GR0(g00,g10,g20); p1=GR0(g01,g11,g21); p2=GR0(g02,g12,g22); break;
    case 1: p0=GR1(g00,g10,g20); p1=GR1(g01,g11,g21); p2=GR1(g02,g12,g22); break;
    case 2: p0=GR2(g00,g10,g20); p1=GR2(g01,g11,g21); p2=GR2(g02,g12,g22); break;
    case 3: p0=GR3(g00,g10,g20); p1=GR3(g01,g11,g21); p2=GR3(g02,g12,g22); break;
    case 4: p0=GR4(g00,g10,g20); p1=GR4(g01,g11,g21); p2=GR4(g02,g12,g22); break;
    default:p0=GR5(g00,g10,g20); p1=GR5(g01,g11,g21); p2=GR5(g02,g12,g22); break;
  }
  const size_t cico = (size_t)ci*1024 + co;
  V[0ull*1048576ull + cico] = GR0(p0,p1,p2);
  V[1ull*1048576ull + cico] = GR1(p0,p1,p2);
  V[2ull*1048576ull + cico] = GR2(p0,p1,p2);
  V[3ull*1048576ull + cico] = GR3(p0,p1,p2);
  V[4ull*1048576ull + cico] = GR4(p0,p1,p2);
  V[5ull*1048576ull + cico] = GR5(p0,p1,p2);
}

// ================= W3: batched fp64 MFMA GEMM  C_c[t,co] = U_c^T x V_c =================
__launch_bounds__(256, 2)
__global__ void wgemm_k(const double* __restrict__ U, const double* __restrict__ V,
                        double* __restrict__ C) {
  __shared__ __align__(16) double As[2][32*64];   // 2 x 16 KB
  __shared__ __align__(16) double Bs[2][32*64];   // 2 x 16 KB
  const int tid = threadIdx.x;
  const int lane = tid & 63;
  const int w = tid >> 6;
  const int wm = w >> 1, wn = w & 1;
  const int l15 = lane & 15, lq = lane >> 4;
  const int bx = blockIdx.x;            // 0..79 = mt*16 + nt
  const int mt = bx >> 4, nt = bx & 15;
  const int t0 = mt * 64, n0 = nt * 64;
  const int z = blockIdx.z;             // slot 0..5
  const double* Ub = U + (size_t)z * (1024ull*USTR);   // [ci][t]
  const double* Vb = V + (size_t)z * 1048576ull;       // [ci][co]
  double* Cb = C + (size_t)z * ((size_t)TPI*1024);

  // ---- layout-proof D probe ----
  int pidx[4], nidx[4];
  {
    dx4 pr = {0.,0.,0.,0.}, pc = {0.,0.,0.,0.};
    pr = MFMA64((double)l15, 1.0, pr);
    pc = MFMA64(1.0, (double)l15, pc);
#pragma unroll
    for (int i = 0; i < 4; ++i) {
      pidx[i] = ((int)pr[i]) >> 2;
      nidx[i] = ((int)pc[i]) >> 2;
    }
  }

  auto stage = [&](int k0s, int slot) {
    char* Ad = (char*)&As[slot][0];
    char* Bd = (char*)&Bs[slot][0];
#pragma unroll
    for (int i = 0; i < 4; ++i) {
      int u = tid + i*256;
      int row = u >> 5, cp = u & 31;
      int t = t0 + 2*cp; if (t > 272) t = 272;   // clamp, stays even/16B-aligned
      gload16(Ub + (size_t)(k0s + row)*USTR + t, Ad + u*16);
    }
#pragma unroll
    for (int i = 0; i < 4; ++i) {
      int u = tid + i*256;
      int row = u >> 5, cp = u & 31;
      gload16(Vb + (size_t)(k0s + row)*1024 + n0 + 2*cp, Bd + u*16);
    }
  };

  dx4 acc[2][2];
#pragma unroll
  for (int i = 0; i < 2; ++i)
#pragma unroll
    for (int j = 0; j < 2; ++j) acc[i][j] = (dx4){0.,0.,0.,0.};

  stage(0, 0);
  __syncthreads();
  int cur = 0;
#pragma unroll 1
  for (int k0 = 0; k0 < 1024; k0 += 32) {
    if (k0 + 32 < 1024) stage(k0 + 32, cur ^ 1);
    const double* Ap = &As[cur][0];
    const double* Bp = &Bs[cur][0];
#pragma unroll
    for (int kk = 0; kk < 32; kk += 4) {
      const int ar = (kk + lq)*64 + wm*32 + l15;
      double a0 = Ap[ar], a1 = Ap[ar + 16];
      const int br = (kk + lq)*64 + wn*32 + l15;
      double b0 = Bp[br], b1 = Bp[br + 16];
      acc[0][0] = MFMA64(a0, b0, acc[0][0]);
      acc[0][1] = MFMA64(a0, b1, acc[0][1]);
      acc[1][0] = MFMA64(a1, b0, acc[1][0]);
      acc[1][1] = MFMA64(a1, b1, acc[1][1]);
    }
    __syncthreads();
    cur ^= 1;
  }

#pragma unroll
  for (int m2 = 0; m2 < 2; ++m2) {
#pragma unroll
    for (int n2 = 0; n2 < 2; ++n2) {
#pragma unroll
      for (int i = 0; i < 4; ++i) {
        int t = t0 + wm*32 + m2*16 + pidx[i];
        int co = n0 + wn*32 + n2*16 + nidx[i];
        if (t < TPI) Cb[(size_t)t*1024 + co] = acc[m2][n2][i];
      }
    }
  }
}

// ================= W4: output transform accumulate into h64[b] as [m][co] =================
__launch_bounds__(256)
__global__ void otrans_k(const double* __restrict__ C, double* __restrict__ h64b,
                         int r) {
  const int g = blockIdx.x*256 + threadIdx.x;   // exactly 273*1024
  const int co = g & 1023, t = g >> 10;
  double m0 = C[((size_t)0*TPI + t)*1024 + co];
  double m1 = C[((size_t)1*TPI + t)*1024 + co];
  double m2 = C[((size_t)2*TPI + t)*1024 + co];
  double m3 = C[((size_t)3*TPI + t)*1024 + co];
  double m4 = C[((size_t)4*TPI + t)*1024 + co];
  double m5 = C[((size_t)5*TPI + t)*1024 + co];
  double s[4];
#pragma unroll
  for (int bb = 0; bb < 4; ++bb)
    s[bb] = ATd[bb][0]*m0 + ATd[bb][1]*m1 + ATd[bb][2]*m2
          + ATd[bb][3]*m3 + ATd[bb][4]*m4 + ATd[bb][5]*m5;
  const int ty = t / 21, tx = t % 21;
#pragma unroll
  for (int a = 0; a < 4; ++a) {
    const int y = ty*4 + a;
    if (y >= HH) continue;
    const double fa = ATd[a][r];
#pragma unroll
    for (int bb = 0; bb < 4; ++bb) {
      const size_t idx = ((size_t)(y*WW + tx*4 + bb))*1024 + co;
      if (r == 0) h64b[idx] = fa * s[bb];
      else        h64b[idx] += fa * s[bb];
    }
  }
}

// ================= W5: finalize h = relu(h64 + bias) -> NCHW f32 (64x64 LDS transpose) =================
__launch_bounds__(256)
__global__ void fin_k(const double* __restrict__ h64, const float* __restrict__ bias,
                      float* __restrict__ h) {
  __shared__ float T[64*65];
  const int m0  = blockIdx.x * 64;     // 66 m-tiles
  const int co0 = blockIdx.y * 64;     // 16 co-groups
  const int b   = blockIdx.z;
  const int tid = threadIdx.x;
#pragma unroll
  for (int i = 0; i < 16; ++i) {
    int e = tid + i*256;
    int mi = e >> 6, coi = e & 63;
    int m = m0 + mi;
    double v = 0.0;
    if (m < HWX) v = h64[((size_t)b*HWX + m)*1024 + co0 + coi];
    T[mi*65 + coi] = (float)fmax(v + (double)bias[co0 + coi], 0.0);
  }
  __syncthreads();
#pragma unroll
  for (int i = 0; i < 16; ++i) {
    int e = tid + i*256;
    int coi = e >> 6, mi = e & 63;
    int m = m0 + mi;
    if (m < HWX) h[((size_t)(b*COUT + co0 + coi))*HWX + m] = T[mi*65 + coi];
  }
}

// ================= K2a: transpose head weights to [c][96] =================
__global__ void wt_k(const float* __restrict__ cls_w, const float* __restrict__ bbox_w,
                     float* __restrict__ wT) {
  int t = blockIdx.x*256 + threadIdx.x;
  if (t >= 96*1024) return;
  int c = t / 96, o = t - (t/96)*96;
  float v = 0.f;
  if (o < 30)      v = cls_w[(size_t)o*1024 + c];
  else if (o < 90) v = bbox_w[(size_t)(o-30)*1024 + c];
  wT[t] = v;
}

// ================= K2: heads as fp64 MFMA GEMM, M=32 tile, 264 blocks =================
__launch_bounds__(256, 2)
__global__ void heads_k(const float* __restrict__ h, const float* __restrict__ wT,
                        const float* __restrict__ cls_b, const float* __restrict__ bbox_b,
                        float* __restrict__ out_cls, float* __restrict__ out_bbox) {
  __shared__ __align__(16) float As[2][32*32];   // 2 x 4 KB  [k][m]
  __shared__ __align__(16) float Bs[2][32*96];   // 2 x 12 KB [k][o]
  const int tid = threadIdx.x;
  const int lane = tid & 63;
  const int w = tid >> 6;
  const int wm = w >> 1, wn = w & 1;     // wave: 16m x 48o
  const int l15 = lane & 15, lq = lane >> 4;
  const int mt = blockIdx.x, b = blockIdx.y;
  const int m0 = mt * 32;

  // ---- layout-proof D probe ----
  int pidx[4], nidx[4];
  {
    dx4 pr = {0.,0.,0.,0.}, pc = {0.,0.,0.,0.};
    pr = MFMA64((double)l15, 1.0, pr);
    pc = MFMA64(1.0, (double)l15, pc);
#pragma unroll
    for (int i = 0; i < 4; ++i) {
      pidx[i] = ((int)pr[i]) >> 2;
      nidx[i] = ((int)pc[i]) >> 2;
    }
  }

  auto stage = [&](int c0, int slot) {
    {
      int row = tid >> 3, cp = tid & 7;
      int mm = m0 + cp*4; if (mm > HWX - 4) mm = HWX - 4;   // 4196, 16B-aligned
      gload16(h + ((size_t)(b*COUT + c0 + row))*HWX + mm,
              (char*)&As[slot][0] + tid*16);
    }
#pragma unroll
    for (int i = 0; i < 3; ++i) {
      int e = tid + i*256;
      int row = e / 24, q = e % 24;
      gload16(wT + (size_t)(c0 + row)*96 + q*4,
              (char*)&Bs[slot][0] + e*16);
    }
  };

  dx4 acc[3];
#pragma unroll
  for (int j = 0; j < 3; ++j) acc[j] = (dx4){0.,0.,0.,0.};

  stage(0, 0);
  __syncthreads();
  int cur = 0;
#pragma unroll 1
  for (int c0 = 0; c0 < CIN; c0 += 32) {
    if (c0 + 32 < CIN) stage(c0 + 32, cur ^ 1);
    const float* Ap = &As[cur][0];
    const float* Bp = &Bs[cur][0];
#pragma unroll
    for (int kk = 0; kk < 32; kk += 4) {
      double a0 = (double)Ap[(kk + lq)*32 + wm*16 + l15];
      const int bb = (kk + lq)*96 + wn*48 + l15;
      double b0 = (double)Bp[bb];
      double b1 = (double)Bp[bb + 16];
      double b2 = (double)Bp[bb + 32];
      acc[0] = MFMA64(a0, b0, acc[0]);
      acc[1] = MFMA64(a0, b1, acc[1]);
      acc[2] = MFMA64(a0, b2, acc[2]);
    }
    __syncthreads();
    cur ^= 1;
  }

#pragma unroll
  for (int nf = 0; nf < 3; ++nf) {
#pragma unroll
    for (int i = 0; i < 4; ++i) {
      int m = m0 + wm*16 + pidx[i];
      int o = wn*48 + nf*16 + nidx[i];
      if (m < HWX) {
        if (o < 30) {
          out_cls[((size_t)(b*30 + o))*HWX + m] =
              (float)(acc[nf][i] + (double)cls_b[o]);
        } else if (o < 90) {
          out_bbox[((size_t)(b*60 + (o - 30)))*HWX + m] =
              (float)(acc[nf][i] + (double)bbox_b[o - 30]);
        }
      }
    }
  }
}

// ================= K2b: scores = sigmoid(l1-l0), fp64 interior =================
__global__ void score_k(const float* __restrict__ out_cls, float* __restrict__ scores) {
  int t = blockIdx.x*256 + threadIdx.x;
  if (t >= BATCH*NSC) return;
  int b = t / NSC; int r = t - b*NSC;
  int m = r / NA;  int a = r - m*NA;
  float l0 = out_cls[((size_t)(b*30 + a))*HWX + m];
  float l1 = out_cls[((size_t)(b*30 + a + NA))*HWX + m];
  double p = 1.0 / (1.0 + exp((double)l0 - (double)l1));
  scores[t] = (float)p;
}

// ================= K3: per-image top-2000, 3-level radix cut + bitonic 4096 =================
// R16: old topk = 198us @ VALUBusy 0.2%. Two causes: (1) scores cluster near 0.5
// (sigmoid of near-zero logits) -> nearly all 63000 keys hit the SAME histogram
// bin -> LDS atomicAdd serializes ~63000 deep (G12 auto-coalescing can't apply:
// data-dependent address). Fix: wave-aggregated hist (ballot-match + one atomic
// per distinct bin per wave). (2) bitonic over CAP=8192 when ~2000 candidates
// suffice. Fix: 3rd radix level (bits 8-15) -> 24-bit cut -> CAP2=4096 sort
// (78 passes x 4/thread vs 91 x 8). Selection semantics identical: candidates
// are a superset of the top-2000, sorted desc by (score_bits, -idx).
__launch_bounds__(1024)
__global__ void topk_k(const float* __restrict__ scores,
                       unsigned* __restrict__ top_idx, float* __restrict__ top_score) {
  __shared__ unsigned hist[256];
  __shared__ unsigned sh_sel, sh_need, sh_cnt;
  __shared__ unsigned long long key[CAP2];
  const int b = blockIdx.x;
  const int tid = threadIdx.x;
  const int lane = tid & 63;
  const float* sc = scores + (size_t)b*NSC;
  const int NIT = (NSC + 1023) / 1024;

  // wave-aggregated histogram add: one atomic per distinct bin per wave
  auto whist = [&](bool act, unsigned bin) {
    unsigned long long alive = __ballot(act);
    while (alive) {
      int leader = __ffsll((long long)alive) - 1;
      unsigned lbin = __shfl(bin, leader);
      unsigned long long match = __ballot(act && (bin == lbin));
      if (lane == leader) atomicAdd(&hist[lbin], (unsigned)__popcll(match));
      alive &= ~match;
      act = act && (bin != lbin);
    }
  };

  // ---- pass A: top byte ----
  if (tid < 256) hist[tid] = 0;
  __syncthreads();
  for (int it = 0; it < NIT; ++it) {
    int i = tid + it*1024;
    bool act = (i < NSC);
    unsigned k = act ? __float_as_uint(sc[i]) : 0u;
    whist(act, k >> 24);
  }
  __syncthreads();
  if (tid == 0) {
    unsigned cum = 0; int bin = 255;
    for (; bin >= 0; --bin) { cum += hist[bin]; if (cum >= TOPN) break; }
    sh_sel  = (unsigned)bin;                    // b1
    sh_need = TOPN - (cum - hist[bin]);
  }
  __syncthreads();
  const unsigned b1 = sh_sel, need1 = sh_need;

  // ---- pass B: bits 16-23 within b1 ----
  if (tid < 256) hist[tid] = 0;
  __syncthreads();
  for (int it = 0; it < NIT; ++it) {
    int i = tid + it*1024;
    bool act = false; unsigned k = 0u;
    if (i < NSC) { k = __float_as_uint(sc[i]); act = ((k >> 24) == b1); }
    whist(act, (k >> 16) & 255u);
  }
  __syncthreads();
  if (tid == 0) {
    unsigned cum = 0; int bin = 255;
    for (; bin >= 0; --bin) { cum += hist[bin]; if (cum >= need1) break; }
    sh_sel  = (b1 << 8) | (unsigned)bin;        // cut16
    sh_need = need1 - (cum - hist[bin]);
  }
  __syncthreads();
  const unsigned cut16 = sh_sel, need2 = sh_need;

  // ---- pass C: bits 8-15 within cut16 -> 24-bit cut ----
  if (tid < 256) hist[tid] = 0;
  __syncthreads();
  for (int it = 0; it < NIT; ++it) {
    int i = tid + it*1024;
    bool act = false; unsigned k = 0u;
    if (i < NSC) { k = __float_as_uint(sc[i]); act = ((k >> 16) == cut16); }
    whist(act, (k >> 8) & 255u);
  }
  __syncthreads();
  if (tid == 0) {
    unsigned cum = 0; int bin = 255;
    for (; bin >= 0; --bin) { cum += hist[bin]; if (cum >= need2) break; }
    sh_sel = (cut16 << 8) | (unsigned)bin;      // cut24
    sh_cnt = 0;
  }
  __syncthreads();
  const unsigned cut24 = sh_sel;

  // ---- compact candidates (wave-aggregated append) ----
  for (int i = tid; i < CAP2; i += 1024) key[i] = 0ull;
  __syncthreads();
  for (int it = 0; it < NIT; ++it) {
    int i = tid + it*1024;
    bool pred = false; unsigned k = 0u;
    if (i < NSC) { k = __float_as_uint(sc[i]); pred = ((k >> 8) >= cut24); }
    unsigned long long m = __ballot(pred);
    if (m) {
      int leader = __ffsll((long long)m) - 1;
      unsigned base = 0;
      if (lane == leader) base = atomicAdd(&sh_cnt, (unsigned)__popcll(m));
      base = __shfl(base, leader);
      if (pred) {
        unsigned p = base + (unsigned)__popcll(m & ((1ull << lane) - 1ull));
        if (p < CAP2)
          key[p] = ((unsigned long long)k << 32) | (unsigned long long)(0xFFFFFFFFu - (unsigned)i);
      }
    }
  }
  __syncthreads();

  // ---- bitonic sort CAP2, DESCENDING by (score_bits, -idx) ----
  for (int k2 = 2; k2 <= CAP2; k2 <<= 1) {
    for (int j = k2 >> 1; j > 0; j >>= 1) {
      for (int i = tid; i < CAP2; i += 1024) {
        int p = i ^ j;
        if (p > i) {
          unsigned long long a = key[i], c = key[p];
          bool up = ((i & k2) == 0);
          if (up ? (a < c) : (a > c)) { key[i] = c; key[p] = a; }
        }
      }
      __syncthreads();
    }
  }
  for (int i = tid; i < TOPN; i += 1024) {
    unsigned long long kk = key[i];
    top_idx[(size_t)b*TOPN + i]   = 0xFFFFFFFFu - (unsigned)(kk & 0xFFFFFFFFull);
    top_score[(size_t)b*TOPN + i] = __uint_as_float((unsigned)(kk >> 32));
  }
}

// ================= K4: decode + clip top boxes (fp64) =================
__global__ void decode_k(const unsigned* __restrict__ top_idx,
                         const float* __restrict__ out_bbox,
                         const float* __restrict__ im_info,
                         double* __restrict__ boxesd) {
  int t = blockIdx.x*256 + threadIdx.x;
  if (t >= BATCH*TOPN) return;
  int b = t / TOPN;
  unsigned idx = top_idx[t];
  int a = idx % NA; int m = idx / NA;
  int yy = m / WW;  int xx = m - yy*WW;
  double sx = (double)xx * 16.0, sy = (double)yy * 16.0;
  double A0 = ANCH[a][0] + sx, A1 = ANCH[a][1] + sy;
  double A2 = ANCH[a][2] + sx, A3 = ANCH[a][3] + sy;
  double w_ = A2 - A0 + 1.0, h_ = A3 - A1 + 1.0;
  double cx = A0 + 0.5*w_,  cy = A1 + 0.5*h_;
  const float* bp = out_bbox + (size_t)b*60*HWX;
  double dx = (double)bp[(a*4+0)*HWX + m];
  double dy = (double)bp[(a*4+1)*HWX + m];
  double dw = fmin((double)bp[(a*4+2)*HWX + m], BBOX_CLIP);
  double dh = fmin((double)bp[(a*4+3)*HWX + m], BBOX_CLIP);
  double pcx = dx*w_ + cx, pcy = dy*h_ + cy;
  double pw = exp(dw)*w_,  ph = exp(dh)*h_;
  double x1 = pcx - 0.5*pw, y1 = pcy - 0.5*ph;
  double x2 = pcx + 0.5*pw - 1.0, y2 = pcy + 0.5*ph - 1.0;
  double hmax = (double)im_info[b*3+0] - 1.0;
  double wmax = (double)im_info[b*3+1] - 1.0;
  x1 = fmin(fmax(x1, 0.0), wmax); x2 = fmin(fmax(x2, 0.0), wmax);
  y1 = fmin(fmax(y1, 0.0), hmax); y2 = fmin(fmax(y2, 0.0), hmax);
  boxesd[(size_t)t*4+0] = x1; boxesd[(size_t)t*4+1] = y1;
  boxesd[(size_t)t*4+2] = x2; boxesd[(size_t)t*4+3] = y2;
}

// ================= K5: IoU suppression bitmask, FULL symmetric rows =================
__launch_bounds__(256)
__global__ void iou_k(const double* __restrict__ boxesd,
                      unsigned long long* __restrict__ mask) {
  __shared__ double BX[TOPN*4];    // 64 KB
  const int b  = blockIdx.y;
  const int i0 = blockIdx.x * 8;
  const double* src = boxesd + (size_t)b*TOPN*4;
  for (int e = threadIdx.x; e < TOPN*4; e += 256) BX[e] = src[e];
  __syncthreads();
  const int il = threadIdx.x >> 5;
  const int w  = threadIdx.x & 31;
  const int i  = i0 + il;
  double x1 = BX[i*4+0], y1 = BX[i*4+1], x2 = BX[i*4+2], y2 = BX[i*4+3];
  double ai = (x2 - x1 + 1.0)*(y2 - y1 + 1.0);
  unsigned long long bits = 0ull;
  for (int jj = 0; jj < 64; ++jj) {
    int j = w*64 + jj;
    if (j >= TOPN) break;
    double bx1 = BX[j*4+0], by1 = BX[j*4+1], bx2 = BX[j*4+2], by2 = BX[j*4+3];
    double xx1 = fmax(x1, bx1), yy1 = fmax(y1, by1);
    double xx2 = fmin(x2, bx2), yy2 = fmin(y2, by2);
    double iw = fmax(xx2 - xx1 + 1.0, 0.0);
    double ih = fmax(yy2 - yy1 + 1.0, 0.0);
    double inter = iw * ih;
    double aj = (bx2 - bx1 + 1.0)*(by2 - by1 + 1.0);
    double iou = inter / (ai + aj - inter);
    if (iou > 0.7) bits |= (1ull << jj);
  }
  mask[((size_t)b*TOPN + i)*32 + w] = bits;
}

// ================= K6: NMS scan — register bitmask + early exit at 300 kept =================
__launch_bounds__(256)
__global__ void nms_out_k(const unsigned long long* __restrict__ mask,
                          const double* __restrict__ boxesd,
                          const float* __restrict__ top_score,
                          float* __restrict__ rois, float* __restrict__ probs) {
  __shared__ unsigned long long MS[256*32];  // 64 KB chunk of mask rows
  __shared__ int kept_idx[POSTN];
  __shared__ int s_cnt, s_done;
  const int b = blockIdx.x;
  const int tid = threadIdx.x;
  if (tid == 0) { s_done = 0; s_cnt = 0; }

  unsigned long long rem = 0ull;     // lane L<32: suppression bits 64L..64L+63
  int cnt = 0;
  const int L = tid;                 // lane id within wave 0 (tid<64)

  for (int ch = 0; ch < 8; ++ch) {
    __syncthreads();
    if (s_done) break;
    const int base = ch * 256;
    for (int e = tid; e < 256*32; e += 256) {
      int row = base + (e >> 5);
      MS[e] = (row < TOPN) ? mask[((size_t)b*TOPN + row)*32 + (e & 31)] : 0ull;
    }
    __syncthreads();
    if (tid < 64) {
      const int lim = (base + 256 < TOPN) ? base + 256 : TOPN;
      int pos = base;
      while (true) {
        unsigned long long wmask = ~rem;
        int lo = pos - 64*L;
        if (lo >= 64) wmask = 0ull;
        else if (lo > 0) wmask &= (~0ull) << lo;
        int hi = lim - 64*L;
        if (hi <= 0) wmask = 0ull;
        else if (hi < 64) wmask &= ((1ull << hi) - 1ull);
        if (L >= 32) wmask = 0ull;
        unsigned long long bal = __ballot(wmask != 0ull);
        if (bal == 0ull) break;
        int lstar = __ffsll((long long)bal) - 1;
        int cand = 64*L + (wmask ? (__ffsll((long long)wmask) - 1) : 0);
        int i = __shfl(cand, lstar);
        if (L == 0) kept_idx[cnt] = i;
        ++cnt;
        if (cnt >= POSTN) {
          if (L == 0) { s_done = 1; }
          break;
        }
        if (L < 32) rem |= MS[(i - base)*32 + L];
        pos = i + 1;
      }
      if (L == 0) s_cnt = cnt;
    }
  }
  __syncthreads();
  const int n = s_cnt;

  // zero-init all rows (coords + probs), batch id column
  for (int j = tid; j < POSTN; j += 256) {
    float* rr = rois + ((size_t)b*POSTN + j)*5;
    rr[0] = (float)b; rr[1] = 0.f; rr[2] = 0.f; rr[3] = 0.f; rr[4] = 0.f;
    probs[(size_t)b*POSTN + j] = 0.f;
  }
  // emit kept boxes in index order (same thread owns row j in both loops)
  for (int j = tid; j < n; j += 256) {
    int i = kept_idx[j];
    const double* bx = boxesd + ((size_t)b*TOPN + i)*4;
    float* rr = rois + ((size_t)b*POSTN + j)*5;
    rr[1] = (float)bx[0]; rr[2] = (float)bx[1];
    rr[3] = (float)bx[2]; rr[4] = (float)bx[3];
    probs[(size_t)b*POSTN + j] = top_score[(size_t)b*TOPN + i];
  }
}

// ================= launch =================
extern "C" void kernel_launch(void* const* d_in, const int* in_sizes, int n_in,
                              void* d_out, int out_size, void* d_ws, size_t ws_size,
                              hipStream_t stream) {
  const float* x      = (const float*)d_in[0];
  const float* conv_w = (const float*)d_in[1];
  const float* conv_b = (const float*)d_in[2];
  const float* cls_w  = (const float*)d_in[3];
  const float* cls_b  = (const float*)d_in[4];
  const float* bbox_w = (const float*)d_in[5];
  const float* bbox_b = (const float*)d_in[6];
  const float* im_info= (const float*)d_in[7];

  float* out  = (float*)d_out;
  float* out_cls  = out + CLS_OFF;
  float* out_bbox = out + BBOX_OFF;
  float* rois     = out + ROIS_OFF;
  float* probs    = out + PROBS_OFF;

  float* wsf = (float*)d_ws;
  float*    wT      = wsf + WS_WT;
  double*   U       = (double*)(wsf + WS_U);
  double*   V       = (double*)(wsf + WS_V);
  double*   Cws     = (double*)(wsf + WS_C);
  double*   h64     = (double*)(wsf + WS_H64);
  // overlays
  float*    h       = wsf + OV_H;      // over V (dead after last wgemm)
  float*    scores  = wsf + OV_SC;     // over C (dead after last otrans)
  unsigned* top_idx = (unsigned*)(wsf + OV_TIDX);
  float*    top_sc  = wsf + OV_TSC;
  double*   boxesd  = (double*)(wsf + OV_BOX);
  unsigned long long* mask = (unsigned long long*)(wsf + OV_MASK);

  wt_k<<<dim3((96*1024 + 255)/256), dim3(256), 0, stream>>>(cls_w, bbox_w, wT);
  for (int r = 0; r < 6; ++r) {
    wtrans_k<<<dim3(4096), dim3(256), 0, stream>>>(conv_w, V, r);   // b-independent: once per r
    for (int b = 0; b < 2; ++b) {
      itrans_k<<<dim3(1664), dim3(256), 0, stream>>>(x, U, b, r);
      wgemm_k<<<dim3(80, 1, 6), dim3(256), 0, stream>>>(U, V, Cws);
      otrans_k<<<dim3(1092), dim3(256), 0, stream>>>(Cws, h64 + (size_t)b*HWX*1024, r);
    }
  }
  fin_k<<<dim3(66, 16, 2), dim3(256), 0, stream>>>(h64, conv_b, h);
  heads_k<<<dim3(132, 2), dim3(256), 0, stream>>>(h, wT, cls_b, bbox_b, out_cls, out_bbox);
  score_k<<<dim3((BATCH*NSC + 255)/256), dim3(256), 0, stream>>>(out_cls, scores);
  topk_k<<<dim3(2), dim3(1024), 0, stream>>>(scores, top_idx, top_sc);
  decode_k<<<dim3((BATCH*TOPN + 255)/256), dim3(256), 0, stream>>>(top_idx, out_bbox, im_info, boxesd);
  iou_k<<<dim3(TOPN/8, 2), dim3(256), 0, stream>>>(boxesd, mask);
  nms_out_k<<<dim3(2), dim3(256), 0, stream>>>(mask, boxesd, top_sc, rois, probs);
}

// Round 8
// 1876.907 us; speedup vs baseline: 1.0905x; 1.0905x over previous
//
#include <hip/hip_runtime.h>
#include <math.h>

// ---------------- problem constants ----------------
#define BATCH   2
#define CIN     1024
#define COUT    1024
#define HH      50
#define WW      84
#define HWX     4200          // 50*84
#define NA      15
#define NSC     63000         // HWX*NA
#define TOPN    2000
#define POSTN   300
#define CAPG    8192          // candidate capacity (16-bit cut, proven R6)
#define CLS_OFF   0           // floats into d_out
#define BBOX_OFF  252000      // 2*30*4200
#define ROIS_OFF  756000      // + 2*60*4200
#define PROBS_OFF 759000      // + 600*5

// Winograd F(4x4,3x3) geometry (per image)
#define TPI 273               // tiles per image (13*21)
#define USTR 274              // padded t-stride (even -> 16B-aligned rows)

__constant__ double ANCH[NA][4] = {
  {-15.0,  -4.0,  30.0, 19.0},
  {-38.0, -16.0,  53.0, 31.0},
  {-84.0, -40.0,  99.0, 55.0},
  {-176.0,-88.0, 191.0,103.0},
  {-360.0,-184.0,375.0,199.0},
  {-8.0,  -8.0,  23.0, 23.0},
  {-24.0, -24.0, 39.0, 39.0},
  {-56.0, -56.0, 71.0, 71.0},
  {-120.0,-120.0,135.0,135.0},
  {-248.0,-248.0,263.0,263.0},
  {-3.0, -14.0, 18.0, 29.0},
  {-14.0, -36.0, 29.0, 51.0},
  {-36.0, -80.0, 51.0, 95.0},
  {-80.0,-168.0, 95.0,183.0},
  {-168.0,-344.0,183.0,359.0}
};

// B^T rows (6x6) for F(4,3)
__constant__ double BTd[6][6] = {
  {4.0,  0.0, -5.0,  0.0, 1.0, 0.0},
  {0.0, -4.0, -4.0,  1.0, 1.0, 0.0},
  {0.0,  4.0, -4.0, -1.0, 1.0, 0.0},
  {0.0, -2.0, -1.0,  2.0, 1.0, 0.0},
  {0.0,  2.0, -1.0, -2.0, 1.0, 0.0},
  {0.0,  4.0,  0.0, -5.0, 0.0, 1.0}
};
// A^T (4x6)
__constant__ double ATd[4][6] = {
  {1.0, 1.0,  1.0, 1.0,  1.0, 0.0},
  {0.0, 1.0, -1.0, 2.0, -2.0, 0.0},
  {0.0, 1.0,  1.0, 4.0,  4.0, 0.0},
  {0.0, 1.0, -1.0, 8.0, -8.0, 1.0}
};

#define BBOX_CLIP 4.1351665567423560     // log(1000/16) in double

// ---------------- workspace float-slot offsets ----------------
// Dense [b][m][co] h64 keeps total at 146.42 MB < R3-proven 148.06 MB.
#define WS_WT     0            // 98,304 f
#define WS_U      98304        // U6: 6*1024*274 f64 = 3,366,912 f
#define WS_V      3465216      // V6: 6*1048576 f64 = 12,582,912 f
#define WS_C      16048128     // C6: 6*273*1024 f64 = 3,354,624 f
#define WS_H64    19402752     // h64: 2*4200*1024 f64 = 17,203,200 f
// end = 36,605,952 f = 146.42 MB
// ---- overlays ----
// h f32 (8,601,600 f) overlays V (dead after last wgemm)
#define OV_H      WS_V
// scores/topk/boxes/mask overlay C (dead after last otrans)
#define OV_SC     (WS_C + 0)        // scores 126,000 f
#define OV_TIDX   (WS_C + 126000)   // 4,000 u32
#define OV_TSC    (WS_C + 130000)   // 4,000 f
#define OV_BOX    (WS_C + 134000)   // 16,000 f64 (32,000 slots)
#define OV_MASK   (WS_C + 166000)   // 128,000 u64 (256,000 slots) -> ends at +422,000
// topk scratch (contiguous, zeroed by tz_k; still far inside C6's 3.35M slots)
#define OV_GH     (WS_C + 422000)   // ghist  2*256 u32
#define OV_GH2    (OV_GH  + 512)    // ghist2 2*256 u32
#define OV_GCA    (OV_GH2 + 512)    // gcutA  2 u32 (pad 16)
#define OV_GCB    (OV_GCA + 16)     // gcutB  2 u32 (pad 16)
#define OV_GCN    (OV_GCB + 16)     // gcnt   2 u32 (pad 16)
#define OV_GK     (OV_GCN + 16)     // gkeys  2*8192 u64 = 32,768 f (8B-aligned)
#define TZ_WORDS  (512 + 512 + 16 + 16 + 16 + 32768)   // 33,840 u32

typedef double dx4 __attribute__((ext_vector_type(4)));

__device__ __forceinline__ void gload16(const void* gptr, void* lptr) {
  __builtin_amdgcn_global_load_lds(
      (const __attribute__((address_space(1))) unsigned int*)gptr,
      (__attribute__((address_space(3))) unsigned int*)lptr, 16, 0, 0);
}
#define MFMA64(a, b, c) __builtin_amdgcn_mfma_f64_16x16x4f64(a, b, c, 0, 0, 0)

// ================= W1: input transform, ONE B^T-row r per launch =================
__launch_bounds__(256)
__global__ void itrans_k(const float* __restrict__ x, double* __restrict__ U,
                         int b, int r) {
  __shared__ float XT[8][6][84];     // 16 KB
  const int bx = blockIdx.x;         // 0..1663 = ty*128 + cg
  const int cg  = bx & 127;
  const int ty  = bx >> 7;
  const int ci0 = cg * 8;
  for (int e = threadIdx.x; e < 4032; e += 256) {
    int ci = e / 504, rem = e % 504;
    int ry = rem / 84, xx = rem % 84;
    int y = ty*4 - 1 + ry;
    float v = 0.f;
    if (y >= 0 && y < HH) v = x[((size_t)(b*CIN + ci0 + ci)*HH + y)*WW + xx];
    XT[ci][ry][xx] = v;
  }
  __syncthreads();
  const int tid = threadIdx.x;
  if (tid < 168) {
    const int ci = tid / 21, tx = tid % 21;
    const double c0 = BTd[r][0], c1 = BTd[r][1], c2 = BTd[r][2];
    const double c3 = BTd[r][3], c4 = BTd[r][4], c5 = BTd[r][5];
    double tt[6];
#pragma unroll
    for (int j = 0; j < 6; ++j) {
      int col = tx*4 - 1 + j;
      double v = 0.0;
      if (col >= 0 && col < WW) {
        v = c0*(double)XT[ci][0][col] + c1*(double)XT[ci][1][col]
          + c2*(double)XT[ci][2][col] + c3*(double)XT[ci][3][col]
          + c4*(double)XT[ci][4][col] + c5*(double)XT[ci][5][col];
      }
      tt[j] = v;
    }
    const int t = ty*21 + tx;
#pragma unroll
    for (int c = 0; c < 6; ++c) {
      double u = BTd[c][0]*tt[0] + BTd[c][1]*tt[1] + BTd[c][2]*tt[2]
               + BTd[c][3]*tt[3] + BTd[c][4]*tt[4] + BTd[c][5]*tt[5];
      U[(size_t)(c*1024 + ci0 + ci)*USTR + t] = u;
    }
  }
}

// ================= W2: weight transform V[c][ci][co] for row r (b-independent) =================
#define GR0(a,b,c) (0.25*(a))
#define GR1(a,b,c) (-((a)+(b)+(c))*(1.0/6.0))
#define GR2(a,b,c) ((-(a)+(b)-(c))*(1.0/6.0))
#define GR3(a,b,c) (((a)+2.0*(b)+4.0*(c))*(1.0/24.0))
#define GR4(a,b,c) (((a)-2.0*(b)+4.0*(c))*(1.0/24.0))
#define GR5(a,b,c) ((c))
__launch_bounds__(256)
__global__ void wtrans_k(const float* __restrict__ conv_w, double* __restrict__ V,
                         int r) {
  const int g = blockIdx.x*256 + threadIdx.x;    // 1,048,576 threads
  const int co = g & 1023, ci = g >> 10;
  const float* gp = conv_w + (size_t)(co*1024 + ci)*9;
  double g00 = (double)gp[0], g01 = (double)gp[1], g02 = (double)gp[2];
  double g10 = (double)gp[3], g11 = (double)gp[4], g12 = (double)gp[5];
  double g20 = (double)gp[6], g21 = (double)gp[7], g22 = (double)gp[8];
  double p0, p1, p2;   // row r of G*g
  switch (r) {
    case 0: p0=GR0(g00,g10,g20); p1=GR0(g01,g11,g21); p2=GR0(g02,g12,g22); break;
    case 1: p0=GR1(g00,g10,g20); p1=GR1(g01,g11,g21); p2=GR1(g02,g12,g22); break;
    case 2: p0=GR2(g00,g10,g20); p1=GR2(g01,g11,g21); p2=GR2(g02,g12,g22); break;
    case 3: p0=GR3(g00,g10,g20); p1=GR3(g01,g11,g21); p2=GR3(g02,g12,g22); break;
    case 4: p0=GR4(g00,g10,g20); p1=GR4(g01,g11,g21); p2=GR4(g02,g12,g22); break;
    default:p0=GR5(g00,g10,g20); p1=GR5(g01,g11,g21); p2=GR5(g02,g12,g22); break;
  }
  const size_t cico = (size_t)ci*1024 + co;
  V[0ull*1048576ull + cico] = GR0(p0,p1,p2);
  V[1ull*1048576ull + cico] = GR1(p0,p1,p2);
  V[2ull*1048576ull + cico] = GR2(p0,p1,p2);
  V[3ull*1048576ull + cico] = GR3(p0,p1,p2);
  V[4ull*1048576ull + cico] = GR4(p0,p1,p2);
  V[5ull*1048576ull + cico] = GR5(p0,p1,p2);
}

// ================= W3: batched fp64 MFMA GEMM  C_c[t,co] = U_c^T x V_c =================
__launch_bounds__(256, 2)
__global__ void wgemm_k(const double* __restrict__ U, const double* __restrict__ V,
                        double* __restrict__ C) {
  __shared__ __align__(16) double As[2][32*64];   // 2 x 16 KB
  __shared__ __align__(16) double Bs[2][32*64];   // 2 x 16 KB
  const int tid = threadIdx.x;
  const int lane = tid & 63;
  const int w = tid >> 6;
  const int wm = w >> 1, wn = w & 1;
  const int l15 = lane & 15, lq = lane >> 4;
  const int bx = blockIdx.x;            // 0..79 = mt*16 + nt
  const int mt = bx >> 4, nt = bx & 15;
  const int t0 = mt * 64, n0 = nt * 64;
  const int z = blockIdx.z;             // slot 0..5
  const double* Ub = U + (size_t)z * (1024ull*USTR);   // [ci][t]
  const double* Vb = V + (size_t)z * 1048576ull;       // [ci][co]
  double* Cb = C + (size_t)z * ((size_t)TPI*1024);

  // ---- layout-proof D probe ----
  int pidx[4], nidx[4];
  {
    dx4 pr = {0.,0.,0.,0.}, pc = {0.,0.,0.,0.};
    pr = MFMA64((double)l15, 1.0, pr);
    pc = MFMA64(1.0, (double)l15, pc);
#pragma unroll
    for (int i = 0; i < 4; ++i) {
      pidx[i] = ((int)pr[i]) >> 2;
      nidx[i] = ((int)pc[i]) >> 2;
    }
  }

  auto stage = [&](int k0s, int slot) {
    char* Ad = (char*)&As[slot][0];
    char* Bd = (char*)&Bs[slot][0];
#pragma unroll
    for (int i = 0; i < 4; ++i) {
      int u = tid + i*256;
      int row = u >> 5, cp = u & 31;
      int t = t0 + 2*cp; if (t > 272) t = 272;   // clamp, stays even/16B-aligned
      gload16(Ub + (size_t)(k0s + row)*USTR + t, Ad + u*16);
    }
#pragma unroll
    for (int i = 0; i < 4; ++i) {
      int u = tid + i*256;
      int row = u >> 5, cp = u & 31;
      gload16(Vb + (size_t)(k0s + row)*1024 + n0 + 2*cp, Bd + u*16);
    }
  };

  dx4 acc[2][2];
#pragma unroll
  for (int i = 0; i < 2; ++i)
#pragma unroll
    for (int j = 0; j < 2; ++j) acc[i][j] = (dx4){0.,0.,0.,0.};

  stage(0, 0);
  __syncthreads();
  int cur = 0;
#pragma unroll 1
  for (int k0 = 0; k0 < 1024; k0 += 32) {
    if (k0 + 32 < 1024) stage(k0 + 32, cur ^ 1);
    const double* Ap = &As[cur][0];
    const double* Bp = &Bs[cur][0];
#pragma unroll
    for (int kk = 0; kk < 32; kk += 4) {
      const int ar = (kk + lq)*64 + wm*32 + l15;
      double a0 = Ap[ar], a1 = Ap[ar + 16];
      const int br = (kk + lq)*64 + wn*32 + l15;
      double b0 = Bp[br], b1 = Bp[br + 16];
      acc[0][0] = MFMA64(a0, b0, acc[0][0]);
      acc[0][1] = MFMA64(a0, b1, acc[0][1]);
      acc[1][0] = MFMA64(a1, b0, acc[1][0]);
      acc[1][1] = MFMA64(a1, b1, acc[1][1]);
    }
    __syncthreads();
    cur ^= 1;
  }

#pragma unroll
  for (int m2 = 0; m2 < 2; ++m2) {
#pragma unroll
    for (int n2 = 0; n2 < 2; ++n2) {
#pragma unroll
      for (int i = 0; i < 4; ++i) {
        int t = t0 + wm*32 + m2*16 + pidx[i];
        int co = n0 + wn*32 + n2*16 + nidx[i];
        if (t < TPI) Cb[(size_t)t*1024 + co] = acc[m2][n2][i];
      }
    }
  }
}

// ================= W4: output transform accumulate into h64[b] as [m][co] =================
__launch_bounds__(256)
__global__ void otrans_k(const double* __restrict__ C, double* __restrict__ h64b,
                         int r) {
  const int g = blockIdx.x*256 + threadIdx.x;   // exactly 273*1024
  const int co = g & 1023, t = g >> 10;
  double m0 = C[((size_t)0*TPI + t)*1024 + co];
  double m1 = C[((size_t)1*TPI + t)*1024 + co];
  double m2 = C[((size_t)2*TPI + t)*1024 + co];
  double m3 = C[((size_t)3*TPI + t)*1024 + co];
  double m4 = C[((size_t)4*TPI + t)*1024 + co];
  double m5 = C[((size_t)5*TPI + t)*1024 + co];
  double s[4];
#pragma unroll
  for (int bb = 0; bb < 4; ++bb)
    s[bb] = ATd[bb][0]*m0 + ATd[bb][1]*m1 + ATd[bb][2]*m2
          + ATd[bb][3]*m3 + ATd[bb][4]*m4 + ATd[bb][5]*m5;
  const int ty = t / 21, tx = t % 21;
#pragma unroll
  for (int a = 0; a < 4; ++a) {
    const int y = ty*4 + a;
    if (y >= HH) continue;
    const double fa = ATd[a][r];
#pragma unroll
    for (int bb = 0; bb < 4; ++bb) {
      const size_t idx = ((size_t)(y*WW + tx*4 + bb))*1024 + co;
      if (r == 0) h64b[idx] = fa * s[bb];
      else        h64b[idx] += fa * s[bb];
    }
  }
}

// ================= W5: finalize h = relu(h64 + bias) -> NCHW f32 (64x64 LDS transpose) =================
__launch_bounds__(256)
__global__ void fin_k(const double* __restrict__ h64, const float* __restrict__ bias,
                      float* __restrict__ h) {
  __shared__ float T[64*65];
  const int m0  = blockIdx.x * 64;     // 66 m-tiles
  const int co0 = blockIdx.y * 64;     // 16 co-groups
  const int b   = blockIdx.z;
  const int tid = threadIdx.x;
#pragma unroll
  for (int i = 0; i < 16; ++i) {
    int e = tid + i*256;
    int mi = e >> 6, coi = e & 63;
    int m = m0 + mi;
    double v = 0.0;
    if (m < HWX) v = h64[((size_t)b*HWX + m)*1024 + co0 + coi];
    T[mi*65 + coi] = (float)fmax(v + (double)bias[co0 + coi], 0.0);
  }
  __syncthreads();
#pragma unroll
  for (int i = 0; i < 16; ++i) {
    int e = tid + i*256;
    int coi = e >> 6, mi = e & 63;
    int m = m0 + mi;
    if (m < HWX) h[((size_t)(b*COUT + co0 + coi))*HWX + m] = T[mi*65 + coi];
  }
}

// ================= K2a: transpose head weights to [c][96] =================
__global__ void wt_k(const float* __restrict__ cls_w, const float* __restrict__ bbox_w,
                     float* __restrict__ wT) {
  int t = blockIdx.x*256 + threadIdx.x;
  if (t >= 96*1024) return;
  int c = t / 96, o = t - (t/96)*96;
  float v = 0.f;
  if (o < 30)      v = cls_w[(size_t)o*1024 + c];
  else if (o < 90) v = bbox_w[(size_t)(o-30)*1024 + c];
  wT[t] = v;
}

// ================= K2: heads as fp64 MFMA GEMM, M=32 tile, 264 blocks =================
__launch_bounds__(256, 2)
__global__ void heads_k(const float* __restrict__ h, const float* __restrict__ wT,
                        const float* __restrict__ cls_b, const float* __restrict__ bbox_b,
                        float* __restrict__ out_cls, float* __restrict__ out_bbox) {
  __shared__ __align__(16) float As[2][32*32];   // 2 x 4 KB  [k][m]
  __shared__ __align__(16) float Bs[2][32*96];   // 2 x 12 KB [k][o]
  const int tid = threadIdx.x;
  const int lane = tid & 63;
  const int w = tid >> 6;
  const int wm = w >> 1, wn = w & 1;     // wave: 16m x 48o
  const int l15 = lane & 15, lq = lane >> 4;
  const int mt = blockIdx.x, b = blockIdx.y;
  const int m0 = mt * 32;

  // ---- layout-proof D probe ----
  int pidx[4], nidx[4];
  {
    dx4 pr = {0.,0.,0.,0.}, pc = {0.,0.,0.,0.};
    pr = MFMA64((double)l15, 1.0, pr);
    pc = MFMA64(1.0, (double)l15, pc);
#pragma unroll
    for (int i = 0; i < 4; ++i) {
      pidx[i] = ((int)pr[i]) >> 2;
      nidx[i] = ((int)pc[i]) >> 2;
    }
  }

  auto stage = [&](int c0, int slot) {
    {
      int row = tid >> 3, cp = tid & 7;
      int mm = m0 + cp*4; if (mm > HWX - 4) mm = HWX - 4;   // 4196, 16B-aligned
      gload16(h + ((size_t)(b*COUT + c0 + row))*HWX + mm,
              (char*)&As[slot][0] + tid*16);
    }
#pragma unroll
    for (int i = 0; i < 3; ++i) {
      int e = tid + i*256;
      int row = e / 24, q = e % 24;
      gload16(wT + (size_t)(c0 + row)*96 + q*4,
              (char*)&Bs[slot][0] + e*16);
    }
  };

  dx4 acc[3];
#pragma unroll
  for (int j = 0; j < 3; ++j) acc[j] = (dx4){0.,0.,0.,0.};

  stage(0, 0);
  __syncthreads();
  int cur = 0;
#pragma unroll 1
  for (int c0 = 0; c0 < CIN; c0 += 32) {
    if (c0 + 32 < CIN) stage(c0 + 32, cur ^ 1);
    const float* Ap = &As[cur][0];
    const float* Bp = &Bs[cur][0];
#pragma unroll
    for (int kk = 0; kk < 32; kk += 4) {
      double a0 = (double)Ap[(kk + lq)*32 + wm*16 + l15];
      const int bb = (kk + lq)*96 + wn*48 + l15;
      double b0 = (double)Bp[bb];
      double b1 = (double)Bp[bb + 16];
      double b2 = (double)Bp[bb + 32];
      acc[0] = MFMA64(a0, b0, acc[0]);
      acc[1] = MFMA64(a0, b1, acc[1]);
      acc[2] = MFMA64(a0, b2, acc[2]);
    }
    __syncthreads();
    cur ^= 1;
  }

#pragma unroll
  for (int nf = 0; nf < 3; ++nf) {
#pragma unroll
    for (int i = 0; i < 4; ++i) {
      int m = m0 + wm*16 + pidx[i];
      int o = wn*48 + nf*16 + nidx[i];
      if (m < HWX) {
        if (o < 30) {
          out_cls[((size_t)(b*30 + o))*HWX + m] =
              (float)(acc[nf][i] + (double)cls_b[o]);
        } else if (o < 90) {
          out_bbox[((size_t)(b*60 + (o - 30)))*HWX + m] =
              (float)(acc[nf][i] + (double)bbox_b[o - 30]);
        }
      }
    }
  }
}

// ================= K2b: scores = sigmoid(l1-l0), fp64 interior =================
__global__ void score_k(const float* __restrict__ out_cls, float* __restrict__ scores) {
  int t = blockIdx.x*256 + threadIdx.x;
  if (t >= BATCH*NSC) return;
  int b = t / NSC; int r = t - b*NSC;
  int m = r / NA;  int a = r - m*NA;
  float l0 = out_cls[((size_t)(b*30 + a))*HWX + m];
  float l1 = out_cls[((size_t)(b*30 + a + NA))*HWX + m];
  double p = 1.0 / (1.0 + exp((double)l0 - (double)l1));
  scores[t] = (float)p;
}

// ================= K3: parallel top-2000 pipeline =================
// R17 post-mortem of R7: wave-aggregated hist REGRESSED (198->325us) — the
// ballot->shfl chain after each load killed memory-level parallelism in a
// 2-block latency-bound kernel (Occ 0.37%). Real fix is BLOCK parallelism:
// split the radix select into small full-GPU dispatches (124 blocks each);
// per-block plain LDS atomics are <=1024-deep and blocks run concurrently.
// Selection semantics identical to the R6-passing kernel: 16-bit radix cut,
// candidates = superset of top-2000, sort desc by (score_bits, ~idx).

// T0: zero topk scratch (ghist/ghist2/cuts/cnt/keys) — one contiguous span
__global__ void tz_k(unsigned* __restrict__ gz) {
  int t = blockIdx.x*256 + threadIdx.x;
  if (t < TZ_WORDS) gz[t] = 0u;
}

// T1: per-block LDS hist of bits 24-31 -> global merge
__launch_bounds__(256)
__global__ void histA_k(const float* __restrict__ scores, unsigned* __restrict__ ghist) {
  __shared__ unsigned lh[256];
  const int b = blockIdx.y;
  const int base = blockIdx.x * 1024;
  lh[threadIdx.x] = 0;
  __syncthreads();
  const float* sc = scores + (size_t)b*NSC;
#pragma unroll
  for (int q = 0; q < 4; ++q) {
    int i = base + threadIdx.x + q*256;
    if (i < NSC) atomicAdd(&lh[__float_as_uint(sc[i]) >> 24], 1u);
  }
  __syncthreads();
  unsigned v = lh[threadIdx.x];
  if (v) atomicAdd(&ghist[b*256 + threadIdx.x], v);
}

// T2: cut A via parallel suffix-scan (no serial 256-load chain)
__launch_bounds__(256)
__global__ void cutA_k(const unsigned* __restrict__ ghist, unsigned* __restrict__ gcutA) {
  __shared__ unsigned s[256];
  const int b = blockIdx.x;
  const int t = threadIdx.x;
  s[t] = ghist[b*256 + t];
  __syncthreads();
  for (int off = 1; off < 256; off <<= 1) {
    unsigned v = (t + off < 256) ? s[t + off] : 0u;
    __syncthreads();
    s[t] += v;
    __syncthreads();
  }
  unsigned cum  = s[t];                       // sum_{j>=t} hist[j]
  unsigned cum1 = (t < 255) ? s[t + 1] : 0u;
  if (cum >= TOPN && (t == 255 || cum1 < TOPN))
    gcutA[b] = ((unsigned)t << 16) | (TOPN - cum1);    // b1 | need
}

// T3: hist of bits 16-23 within top-byte bin b1
__launch_bounds__(256)
__global__ void histB_k(const float* __restrict__ scores, const unsigned* __restrict__ gcutA,
                        unsigned* __restrict__ ghist2) {
  __shared__ unsigned lh[256];
  const int b = blockIdx.y;
  const unsigned b1 = gcutA[b] >> 16;
  const int base = blockIdx.x * 1024;
  lh[threadIdx.x] = 0;
  __syncthreads();
  const float* sc = scores + (size_t)b*NSC;
#pragma unroll
  for (int q = 0; q < 4; ++q) {
    int i = base + threadIdx.x + q*256;
    if (i < NSC) {
      unsigned k = __float_as_uint(sc[i]);
      if ((k >> 24) == b1) atomicAdd(&lh[(k >> 16) & 255u], 1u);
    }
  }
  __syncthreads();
  unsigned v = lh[threadIdx.x];
  if (v) atomicAdd(&ghist2[b*256 + threadIdx.x], v);
}

// T4: cut B -> 16-bit cut
__launch_bounds__(256)
__global__ void cutB_k(const unsigned* __restrict__ ghist2, const unsigned* __restrict__ gcutA,
                       unsigned* __restrict__ gcutB) {
  __shared__ unsigned s[256];
  const int b = blockIdx.x;
  const int t = threadIdx.x;
  const unsigned b1 = gcutA[b] >> 16, need = gcutA[b] & 0xFFFFu;
  s[t] = ghist2[b*256 + t];
  __syncthreads();
  for (int off = 1; off < 256; off <<= 1) {
    unsigned v = (t + off < 256) ? s[t + off] : 0u;
    __syncthreads();
    s[t] += v;
    __syncthreads();
  }
  unsigned cum  = s[t];
  unsigned cum1 = (t < 255) ? s[t + 1] : 0u;
  if (cum >= need && (t == 255 || cum1 < need))
    gcutB[b] = (b1 << 8) | (unsigned)t;                // cut16
}

// T5: compact candidates (wave-aggregated global append; order irrelevant)
__launch_bounds__(256)
__global__ void compact_k(const float* __restrict__ scores, const unsigned* __restrict__ gcutB,
                          unsigned long long* __restrict__ gkeys, unsigned* __restrict__ gcnt) {
  const int b = blockIdx.y;
  const unsigned cut = gcutB[b];
  const int base = blockIdx.x * 1024;
  const int lane = threadIdx.x & 63;
  const float* sc = scores + (size_t)b*NSC;
#pragma unroll
  for (int q = 0; q < 4; ++q) {
    int i = base + threadIdx.x + q*256;
    bool pred = false; unsigned k = 0u;
    if (i < NSC) { k = __float_as_uint(sc[i]); pred = ((k >> 16) >= cut); }
    unsigned long long m = __ballot(pred);
    if (m) {
      int leader = __ffsll((long long)m) - 1;
      unsigned bp = 0;
      if (lane == leader) bp = atomicAdd(&gcnt[b], (unsigned)__popcll(m));
      bp = __shfl(bp, leader);
      if (pred) {
        unsigned p = bp + (unsigned)__popcll(m & ((1ull << lane) - 1ull));
        if (p < CAPG)
          gkeys[(size_t)b*CAPG + p] =
              ((unsigned long long)k << 32) | (unsigned long long)(0xFFFFFFFFu - (unsigned)i);
      }
    }
  }
}

// T6: bitonic sort 8192 + emit top-2000 (keys pre-zeroed by tz_k -> pads sink)
__launch_bounds__(1024)
__global__ void sortk_k(const unsigned long long* __restrict__ gkeys,
                        unsigned* __restrict__ top_idx, float* __restrict__ top_score) {
  __shared__ unsigned long long key[CAPG];   // 64 KB
  const int b = blockIdx.x;
  const int tid = threadIdx.x;
  for (int i = tid; i < CAPG; i += 1024) key[i] = gkeys[(size_t)b*CAPG + i];
  __syncthreads();
  for (int k2 = 2; k2 <= CAPG; k2 <<= 1) {
    for (int j = k2 >> 1; j > 0; j >>= 1) {
      for (int i = tid; i < CAPG; i += 1024) {
        int p = i ^ j;
        if (p > i) {
          unsigned long long a = key[i], c = key[p];
          bool up = ((i & k2) == 0);
          if (up ? (a < c) : (a > c)) { key[i] = c; key[p] = a; }
        }
      }
      __syncthreads();
    }
  }
  for (int i = tid; i < TOPN; i += 1024) {
    unsigned long long kk = key[i];
    top_idx[(size_t)b*TOPN + i]   = 0xFFFFFFFFu - (unsigned)(kk & 0xFFFFFFFFull);
    top_score[(size_t)b*TOPN + i] = __uint_as_float((unsigned)(kk >> 32));
  }
}

// ================= K4: decode + clip top boxes (fp64) =================
__global__ void decode_k(const unsigned* __restrict__ top_idx,
                         const float* __restrict__ out_bbox,
                         const float* __restrict__ im_info,
                         double* __restrict__ boxesd) {
  int t = blockIdx.x*256 + threadIdx.x;
  if (t >= BATCH*TOPN) return;
  int b = t / TOPN;
  unsigned idx = top_idx[t];
  int a = idx % NA; int m = idx / NA;
  int yy = m / WW;  int xx = m - yy*WW;
  double sx = (double)xx * 16.0, sy = (double)yy * 16.0;
  double A0 = ANCH[a][0] + sx, A1 = ANCH[a][1] + sy;
  double A2 = ANCH[a][2] + sx, A3 = ANCH[a][3] + sy;
  double w_ = A2 - A0 + 1.0, h_ = A3 - A1 + 1.0;
  double cx = A0 + 0.5*w_,  cy = A1 + 0.5*h_;
  const float* bp = out_bbox + (size_t)b*60*HWX;
  double dx = (double)bp[(a*4+0)*HWX + m];
  double dy = (double)bp[(a*4+1)*HWX + m];
  double dw = fmin((double)bp[(a*4+2)*HWX + m], BBOX_CLIP);
  double dh = fmin((double)bp[(a*4+3)*HWX + m], BBOX_CLIP);
  double pcx = dx*w_ + cx, pcy = dy*h_ + cy;
  double pw = exp(dw)*w_,  ph = exp(dh)*h_;
  double x1 = pcx - 0.5*pw, y1 = pcy - 0.5*ph;
  double x2 = pcx + 0.5*pw - 1.0, y2 = pcy + 0.5*ph - 1.0;
  double hmax = (double)im_info[b*3+0] - 1.0;
  double wmax = (double)im_info[b*3+1] - 1.0;
  x1 = fmin(fmax(x1, 0.0), wmax); x2 = fmin(fmax(x2, 0.0), wmax);
  y1 = fmin(fmax(y1, 0.0), hmax); y2 = fmin(fmax(y2, 0.0), hmax);
  boxesd[(size_t)t*4+0] = x1; boxesd[(size_t)t*4+1] = y1;
  boxesd[(size_t)t*4+2] = x2; boxesd[(size_t)t*4+3] = y2;
}

// ================= K5: IoU suppression bitmask, FULL symmetric rows =================
__launch_bounds__(256)
__global__ void iou_k(const double* __restrict__ boxesd,
                      unsigned long long* __restrict__ mask) {
  __shared__ double BX[TOPN*4];    // 64 KB
  const int b  = blockIdx.y;
  const int i0 = blockIdx.x * 8;
  const double* src = boxesd + (size_t)b*TOPN*4;
  for (int e = threadIdx.x; e < TOPN*4; e += 256) BX[e] = src[e];
  __syncthreads();
  const int il = threadIdx.x >> 5;
  const int w  = threadIdx.x & 31;
  const int i  = i0 + il;
  double x1 = BX[i*4+0], y1 = BX[i*4+1], x2 = BX[i*4+2], y2 = BX[i*4+3];
  double ai = (x2 - x1 + 1.0)*(y2 - y1 + 1.0);
  unsigned long long bits = 0ull;
  for (int jj = 0; jj < 64; ++jj) {
    int j = w*64 + jj;
    if (j >= TOPN) break;
    double bx1 = BX[j*4+0], by1 = BX[j*4+1], bx2 = BX[j*4+2], by2 = BX[j*4+3];
    double xx1 = fmax(x1, bx1), yy1 = fmax(y1, by1);
    double xx2 = fmin(x2, bx2), yy2 = fmin(y2, by2);
    double iw = fmax(xx2 - xx1 + 1.0, 0.0);
    double ih = fmax(yy2 - yy1 + 1.0, 0.0);
    double inter = iw * ih;
    double aj = (bx2 - bx1 + 1.0)*(by2 - by1 + 1.0);
    double iou = inter / (ai + aj - inter);
    if (iou > 0.7) bits |= (1ull << jj);
  }
  mask[((size_t)b*TOPN + i)*32 + w] = bits;
}

// ================= K6: NMS scan — register bitmask + early exit at 300 kept =================
__launch_bounds__(256)
__global__ void nms_out_k(const unsigned long long* __restrict__ mask,
                          const double* __restrict__ boxesd,
                          const float* __restrict__ top_score,
                          float* __restrict__ rois, float* __restrict__ probs) {
  __shared__ unsigned long long MS[256*32];  // 64 KB chunk of mask rows
  __shared__ int kept_idx[POSTN];
  __shared__ int s_cnt, s_done;
  const int b = blockIdx.x;
  const int tid = threadIdx.x;
  if (tid == 0) { s_done = 0; s_cnt = 0; }

  unsigned long long rem = 0ull;     // lane L<32: suppression bits 64L..64L+63
  int cnt = 0;
  const int L = tid;                 // lane id within wave 0 (tid<64)

  for (int ch = 0; ch < 8; ++ch) {
    __syncthreads();
    if (s_done) break;
    const int base = ch * 256;
    for (int e = tid; e < 256*32; e += 256) {
      int row = base + (e >> 5);
      MS[e] = (row < TOPN) ? mask[((size_t)b*TOPN + row)*32 + (e & 31)] : 0ull;
    }
    __syncthreads();
    if (tid < 64) {
      const int lim = (base + 256 < TOPN) ? base + 256 : TOPN;
      int pos = base;
      while (true) {
        unsigned long long wmask = ~rem;
        int lo = pos - 64*L;
        if (lo >= 64) wmask = 0ull;
        else if (lo > 0) wmask &= (~0ull) << lo;
        int hi = lim - 64*L;
        if (hi <= 0) wmask = 0ull;
        else if (hi < 64) wmask &= ((1ull << hi) - 1ull);
        if (L >= 32) wmask = 0ull;
        unsigned long long bal = __ballot(wmask != 0ull);
        if (bal == 0ull) break;
        int lstar = __ffsll((long long)bal) - 1;
        int cand = 64*L + (wmask ? (__ffsll((long long)wmask) - 1) : 0);
        int i = __shfl(cand, lstar);
        if (L == 0) kept_idx[cnt] = i;
        ++cnt;
        if (cnt >= POSTN) {
          if (L == 0) { s_done = 1; }
          break;
        }
        if (L < 32) rem |= MS[(i - base)*32 + L];
        pos = i + 1;
      }
      if (L == 0) s_cnt = cnt;
    }
  }
  __syncthreads();
  const int n = s_cnt;

  // zero-init all rows (coords + probs), batch id column
  for (int j = tid; j < POSTN; j += 256) {
    float* rr = rois + ((size_t)b*POSTN + j)*5;
    rr[0] = (float)b; rr[1] = 0.f; rr[2] = 0.f; rr[3] = 0.f; rr[4] = 0.f;
    probs[(size_t)b*POSTN + j] = 0.f;
  }
  // emit kept boxes in index order (same thread owns row j in both loops)
  for (int j = tid; j < n; j += 256) {
    int i = kept_idx[j];
    const double* bx = boxesd + ((size_t)b*TOPN + i)*4;
    float* rr = rois + ((size_t)b*POSTN + j)*5;
    rr[1] = (float)bx[0]; rr[2] = (float)bx[1];
    rr[3] = (float)bx[2]; rr[4] = (float)bx[3];
    probs[(size_t)b*POSTN + j] = top_score[(size_t)b*TOPN + i];
  }
}

// ================= launch =================
extern "C" void kernel_launch(void* const* d_in, const int* in_sizes, int n_in,
                              void* d_out, int out_size, void* d_ws, size_t ws_size,
                              hipStream_t stream) {
  const float* x      = (const float*)d_in[0];
  const float* conv_w = (const float*)d_in[1];
  const float* conv_b = (const float*)d_in[2];
  const float* cls_w  = (const float*)d_in[3];
  const float* cls_b  = (const float*)d_in[4];
  const float* bbox_w = (const float*)d_in[5];
  const float* bbox_b = (const float*)d_in[6];
  const float* im_info= (const float*)d_in[7];

  float* out  = (float*)d_out;
  float* out_cls  = out + CLS_OFF;
  float* out_bbox = out + BBOX_OFF;
  float* rois     = out + ROIS_OFF;
  float* probs    = out + PROBS_OFF;

  float* wsf = (float*)d_ws;
  float*    wT      = wsf + WS_WT;
  double*   U       = (double*)(wsf + WS_U);
  double*   V       = (double*)(wsf + WS_V);
  double*   Cws     = (double*)(wsf + WS_C);
  double*   h64     = (double*)(wsf + WS_H64);
  // overlays
  float*    h       = wsf + OV_H;      // over V (dead after last wgemm)
  float*    scores  = wsf + OV_SC;     // over C (dead after last otrans)
  unsigned* top_idx = (unsigned*)(wsf + OV_TIDX);
  float*    top_sc  = wsf + OV_TSC;
  double*   boxesd  = (double*)(wsf + OV_BOX);
  unsigned long long* mask = (unsigned long long*)(wsf + OV_MASK);
  unsigned* ghist   = (unsigned*)(wsf + OV_GH);
  unsigned* ghist2  = (unsigned*)(wsf + OV_GH2);
  unsigned* gcutA   = (unsigned*)(wsf + OV_GCA);
  unsigned* gcutB   = (unsigned*)(wsf + OV_GCB);
  unsigned* gcnt    = (unsigned*)(wsf + OV_GCN);
  unsigned long long* gkeys = (unsigned long long*)(wsf + OV_GK);

  wt_k<<<dim3((96*1024 + 255)/256), dim3(256), 0, stream>>>(cls_w, bbox_w, wT);
  for (int r = 0; r < 6; ++r) {
    wtrans_k<<<dim3(4096), dim3(256), 0, stream>>>(conv_w, V, r);   // b-independent: once per r
    for (int b = 0; b < 2; ++b) {
      itrans_k<<<dim3(1664), dim3(256), 0, stream>>>(x, U, b, r);
      wgemm_k<<<dim3(80, 1, 6), dim3(256), 0, stream>>>(U, V, Cws);
      otrans_k<<<dim3(1092), dim3(256), 0, stream>>>(Cws, h64 + (size_t)b*HWX*1024, r);
    }
  }
  fin_k<<<dim3(66, 16, 2), dim3(256), 0, stream>>>(h64, conv_b, h);
  heads_k<<<dim3(132, 2), dim3(256), 0, stream>>>(h, wT, cls_b, bbox_b, out_cls, out_bbox);
  tz_k<<<dim3((TZ_WORDS + 255)/256), dim3(256), 0, stream>>>(ghist);
  score_k<<<dim3((BATCH*NSC + 255)/256), dim3(256), 0, stream>>>(out_cls, scores);
  histA_k<<<dim3(62, 2), dim3(256), 0, stream>>>(scores, ghist);
  cutA_k<<<dim3(2), dim3(256), 0, stream>>>(ghist, gcutA);
  histB_k<<<dim3(62, 2), dim3(256), 0, stream>>>(scores, gcutA, ghist2);
  cutB_k<<<dim3(2), dim3(256), 0, stream>>>(ghist2, gcutA, gcutB);
  compact_k<<<dim3(62, 2), dim3(256), 0, stream>>>(scores, gcutB, gkeys, gcnt);
  sortk_k<<<dim3(2), dim3(1024), 0, stream>>>(gkeys, top_idx, top_sc);
  decode_k<<<dim3((BATCH*TOPN + 255)/256), dim3(256), 0, stream>>>(top_idx, out_bbox, im_info, boxesd);
  iou_k<<<dim3(TOPN/8, 2), dim3(256), 0, stream>>>(boxesd, mask);
  nms_out_k<<<dim3(2), dim3(256), 0, stream>>>(mask, boxesd, top_sc, rois, probs);
}

// Round 9
// 1792.577 us; speedup vs baseline: 1.1418x; 1.0470x over previous
//
#include <hip/hip_runtime.h>
#include <math.h>

// ---------------- problem constants ----------------
#define BATCH   2
#define CIN     1024
#define COUT    1024
#define HH      50
#define WW      84
#define HWX     4200          // 50*84
#define NA      15
#define NSC     63000         // HWX*NA
#define TOPN    2000
#define POSTN   300
#define CAPG    8192          // candidate capacity (16-bit cut, proven R6)
#define CLS_OFF   0           // floats into d_out
#define BBOX_OFF  252000      // 2*30*4200
#define ROIS_OFF  756000      // + 2*60*4200
#define PROBS_OFF 759000      // + 600*5

// Winograd F(4x4,3x3) geometry (per image)
#define TPI 273               // tiles per image (13*21)
#define USTR 274              // padded t-stride (even -> 16B-aligned rows)

__constant__ double ANCH[NA][4] = {
  {-15.0,  -4.0,  30.0, 19.0},
  {-38.0, -16.0,  53.0, 31.0},
  {-84.0, -40.0,  99.0, 55.0},
  {-176.0,-88.0, 191.0,103.0},
  {-360.0,-184.0,375.0,199.0},
  {-8.0,  -8.0,  23.0, 23.0},
  {-24.0, -24.0, 39.0, 39.0},
  {-56.0, -56.0, 71.0, 71.0},
  {-120.0,-120.0,135.0,135.0},
  {-248.0,-248.0,263.0,263.0},
  {-3.0, -14.0, 18.0, 29.0},
  {-14.0, -36.0, 29.0, 51.0},
  {-36.0, -80.0, 51.0, 95.0},
  {-80.0,-168.0, 95.0,183.0},
  {-168.0,-344.0,183.0,359.0}
};

// B^T rows (6x6) for F(4,3)
__constant__ double BTd[6][6] = {
  {4.0,  0.0, -5.0,  0.0, 1.0, 0.0},
  {0.0, -4.0, -4.0,  1.0, 1.0, 0.0},
  {0.0,  4.0, -4.0, -1.0, 1.0, 0.0},
  {0.0, -2.0, -1.0,  2.0, 1.0, 0.0},
  {0.0,  2.0, -1.0, -2.0, 1.0, 0.0},
  {0.0,  4.0,  0.0, -5.0, 0.0, 1.0}
};
// A^T (4x6)
__constant__ double ATd[4][6] = {
  {1.0, 1.0,  1.0, 1.0,  1.0, 0.0},
  {0.0, 1.0, -1.0, 2.0, -2.0, 0.0},
  {0.0, 1.0,  1.0, 4.0,  4.0, 0.0},
  {0.0, 1.0, -1.0, 8.0, -8.0, 1.0}
};

#define BBOX_CLIP 4.1351665567423560     // log(1000/16) in double

// ---------------- workspace float-slot offsets ----------------
// Dense [b][m][co] h64 keeps total at 146.42 MB < R3-proven 148.06 MB.
#define WS_WT     0            // 98,304 f
#define WS_U      98304        // U6: 6*1024*274 f64 = 3,366,912 f
#define WS_V      3465216      // V6: 6*1048576 f64 = 12,582,912 f
#define WS_C      16048128     // C6: 6*273*1024 f64 = 3,354,624 f
#define WS_H64    19402752     // h64: 2*4200*1024 f64 = 17,203,200 f
// end = 36,605,952 f = 146.42 MB
// ---- overlays ----
// h f32 (8,601,600 f) overlays V (dead after last wgemm)
#define OV_H      WS_V
// scores/topk/boxes/mask overlay C (dead after last otrans)
#define OV_SC     (WS_C + 0)        // scores 126,000 f
#define OV_TIDX   (WS_C + 126000)   // 4,000 u32
#define OV_TSC    (WS_C + 130000)   // 4,000 f
#define OV_BOX    (WS_C + 134000)   // 16,000 f64 (32,000 slots)
#define OV_MASK   (WS_C + 166000)   // 128,000 u64 (256,000 slots) -> ends at +422,000
// topk scratch (hists/cuts/cnt zeroed by tz_k; gkeys needs NO zeroing: rank_k
// only scans j < gcnt)
#define OV_GH     (WS_C + 422000)   // ghist  2*256 u32
#define OV_GH2    (OV_GH  + 512)    // ghist2 2*256 u32
#define OV_GCA    (OV_GH2 + 512)    // gcutA  2 u32 (pad 16)
#define OV_GCB    (OV_GCA + 16)     // gcutB  2 u32 (pad 16)
#define OV_GCN    (OV_GCB + 16)     // gcnt   2 u32 (pad 16)
#define OV_GK     (OV_GCN + 16)     // gkeys  2*8192 u64 = 32,768 f (8B-aligned)
#define TZ_WORDS  (512 + 512 + 16 + 16 + 16)   // 1,072 u32

typedef double dx4 __attribute__((ext_vector_type(4)));

__device__ __forceinline__ void gload16(const void* gptr, void* lptr) {
  __builtin_amdgcn_global_load_lds(
      (const __attribute__((address_space(1))) unsigned int*)gptr,
      (__attribute__((address_space(3))) unsigned int*)lptr, 16, 0, 0);
}
#define MFMA64(a, b, c) __builtin_amdgcn_mfma_f64_16x16x4f64(a, b, c, 0, 0, 0)

// ================= W1: input transform, ONE B^T-row r per launch =================
__launch_bounds__(256)
__global__ void itrans_k(const float* __restrict__ x, double* __restrict__ U,
                         int b, int r) {
  __shared__ float XT[8][6][84];     // 16 KB
  const int bx = blockIdx.x;         // 0..1663 = ty*128 + cg
  const int cg  = bx & 127;
  const int ty  = bx >> 7;
  const int ci0 = cg * 8;
  for (int e = threadIdx.x; e < 4032; e += 256) {
    int ci = e / 504, rem = e % 504;
    int ry = rem / 84, xx = rem % 84;
    int y = ty*4 - 1 + ry;
    float v = 0.f;
    if (y >= 0 && y < HH) v = x[((size_t)(b*CIN + ci0 + ci)*HH + y)*WW + xx];
    XT[ci][ry][xx] = v;
  }
  __syncthreads();
  const int tid = threadIdx.x;
  if (tid < 168) {
    const int ci = tid / 21, tx = tid % 21;
    const double c0 = BTd[r][0], c1 = BTd[r][1], c2 = BTd[r][2];
    const double c3 = BTd[r][3], c4 = BTd[r][4], c5 = BTd[r][5];
    double tt[6];
#pragma unroll
    for (int j = 0; j < 6; ++j) {
      int col = tx*4 - 1 + j;
      double v = 0.0;
      if (col >= 0 && col < WW) {
        v = c0*(double)XT[ci][0][col] + c1*(double)XT[ci][1][col]
          + c2*(double)XT[ci][2][col] + c3*(double)XT[ci][3][col]
          + c4*(double)XT[ci][4][col] + c5*(double)XT[ci][5][col];
      }
      tt[j] = v;
    }
    const int t = ty*21 + tx;
#pragma unroll
    for (int c = 0; c < 6; ++c) {
      double u = BTd[c][0]*tt[0] + BTd[c][1]*tt[1] + BTd[c][2]*tt[2]
               + BTd[c][3]*tt[3] + BTd[c][4]*tt[4] + BTd[c][5]*tt[5];
      U[(size_t)(c*1024 + ci0 + ci)*USTR + t] = u;
    }
  }
}

// ================= W2: weight transform V[c][ci][co] for row r (b-independent) =================
#define GR0(a,b,c) (0.25*(a))
#define GR1(a,b,c) (-((a)+(b)+(c))*(1.0/6.0))
#define GR2(a,b,c) ((-(a)+(b)-(c))*(1.0/6.0))
#define GR3(a,b,c) (((a)+2.0*(b)+4.0*(c))*(1.0/24.0))
#define GR4(a,b,c) (((a)-2.0*(b)+4.0*(c))*(1.0/24.0))
#define GR5(a,b,c) ((c))
__launch_bounds__(256)
__global__ void wtrans_k(const float* __restrict__ conv_w, double* __restrict__ V,
                         int r) {
  const int g = blockIdx.x*256 + threadIdx.x;    // 1,048,576 threads
  const int co = g & 1023, ci = g >> 10;
  const float* gp = conv_w + (size_t)(co*1024 + ci)*9;
  double g00 = (double)gp[0], g01 = (double)gp[1], g02 = (double)gp[2];
  double g10 = (double)gp[3], g11 = (double)gp[4], g12 = (double)gp[5];
  double g20 = (double)gp[6], g21 = (double)gp[7], g22 = (double)gp[8];
  double p0, p1, p2;   // row r of G*g
  switch (r) {
    case 0: p0=GR0(g00,g10,g20); p1=GR0(g01,g11,g21); p2=GR0(g02,g12,g22); break;
    case 1: p0=GR1(g00,g10,g20); p1=GR1(g01,g11,g21); p2=GR1(g02,g12,g22); break;
    case 2: p0=GR2(g00,g10,g20); p1=GR2(g01,g11,g21); p2=GR2(g02,g12,g22); break;
    case 3: p0=GR3(g00,g10,g20); p1=GR3(g01,g11,g21); p2=GR3(g02,g12,g22); break;
    case 4: p0=GR4(g00,g10,g20); p1=GR4(g01,g11,g21); p2=GR4(g02,g12,g22); break;
    default:p0=GR5(g00,g10,g20); p1=GR5(g01,g11,g21); p2=GR5(g02,g12,g22); break;
  }
  const size_t cico = (size_t)ci*1024 + co;
  V[0ull*1048576ull + cico] = GR0(p0,p1,p2);
  V[1ull*1048576ull + cico] = GR1(p0,p1,p2);
  V[2ull*1048576ull + cico] = GR2(p0,p1,p2);
  V[3ull*1048576ull + cico] = GR3(p0,p1,p2);
  V[4ull*1048576ull + cico] = GR4(p0,p1,p2);
  V[5ull*1048576ull + cico] = GR5(p0,p1,p2);
}

// ================= W3: batched fp64 MFMA GEMM  C_c[t,co] = U_c^T x V_c =================
__launch_bounds__(256, 2)
__global__ void wgemm_k(const double* __restrict__ U, const double* __restrict__ V,
                        double* __restrict__ C) {
  __shared__ __align__(16) double As[2][32*64];   // 2 x 16 KB
  __shared__ __align__(16) double Bs[2][32*64];   // 2 x 16 KB
  const int tid = threadIdx.x;
  const int lane = tid & 63;
  const int w = tid >> 6;
  const int wm = w >> 1, wn = w & 1;
  const int l15 = lane & 15, lq = lane >> 4;
  const int bx = blockIdx.x;            // 0..79 = mt*16 + nt
  const int mt = bx >> 4, nt = bx & 15;
  const int t0 = mt * 64, n0 = nt * 64;
  const int z = blockIdx.z;             // slot 0..5
  const double* Ub = U + (size_t)z * (1024ull*USTR);   // [ci][t]
  const double* Vb = V + (size_t)z * 1048576ull;       // [ci][co]
  double* Cb = C + (size_t)z * ((size_t)TPI*1024);

  // ---- layout-proof D probe ----
  int pidx[4], nidx[4];
  {
    dx4 pr = {0.,0.,0.,0.}, pc = {0.,0.,0.,0.};
    pr = MFMA64((double)l15, 1.0, pr);
    pc = MFMA64(1.0, (double)l15, pc);
#pragma unroll
    for (int i = 0; i < 4; ++i) {
      pidx[i] = ((int)pr[i]) >> 2;
      nidx[i] = ((int)pc[i]) >> 2;
    }
  }

  auto stage = [&](int k0s, int slot) {
    char* Ad = (char*)&As[slot][0];
    char* Bd = (char*)&Bs[slot][0];
#pragma unroll
    for (int i = 0; i < 4; ++i) {
      int u = tid + i*256;
      int row = u >> 5, cp = u & 31;
      int t = t0 + 2*cp; if (t > 272) t = 272;   // clamp, stays even/16B-aligned
      gload16(Ub + (size_t)(k0s + row)*USTR + t, Ad + u*16);
    }
#pragma unroll
    for (int i = 0; i < 4; ++i) {
      int u = tid + i*256;
      int row = u >> 5, cp = u & 31;
      gload16(Vb + (size_t)(k0s + row)*1024 + n0 + 2*cp, Bd + u*16);
    }
  };

  dx4 acc[2][2];
#pragma unroll
  for (int i = 0; i < 2; ++i)
#pragma unroll
    for (int j = 0; j < 2; ++j) acc[i][j] = (dx4){0.,0.,0.,0.};

  stage(0, 0);
  __syncthreads();
  int cur = 0;
#pragma unroll 1
  for (int k0 = 0; k0 < 1024; k0 += 32) {
    if (k0 + 32 < 1024) stage(k0 + 32, cur ^ 1);
    const double* Ap = &As[cur][0];
    const double* Bp = &Bs[cur][0];
#pragma unroll
    for (int kk = 0; kk < 32; kk += 4) {
      const int ar = (kk + lq)*64 + wm*32 + l15;
      double a0 = Ap[ar], a1 = Ap[ar + 16];
      const int br = (kk + lq)*64 + wn*32 + l15;
      double b0 = Bp[br], b1 = Bp[br + 16];
      acc[0][0] = MFMA64(a0, b0, acc[0][0]);
      acc[0][1] = MFMA64(a0, b1, acc[0][1]);
      acc[1][0] = MFMA64(a1, b0, acc[1][0]);
      acc[1][1] = MFMA64(a1, b1, acc[1][1]);
    }
    __syncthreads();
    cur ^= 1;
  }

#pragma unroll
  for (int m2 = 0; m2 < 2; ++m2) {
#pragma unroll
    for (int n2 = 0; n2 < 2; ++n2) {
#pragma unroll
      for (int i = 0; i < 4; ++i) {
        int t = t0 + wm*32 + m2*16 + pidx[i];
        int co = n0 + wn*32 + n2*16 + nidx[i];
        if (t < TPI) Cb[(size_t)t*1024 + co] = acc[m2][n2][i];
      }
    }
  }
}

// ================= W4: output transform accumulate into h64[b] as [m][co] =================
__launch_bounds__(256)
__global__ void otrans_k(const double* __restrict__ C, double* __restrict__ h64b,
                         int r) {
  const int g = blockIdx.x*256 + threadIdx.x;   // exactly 273*1024
  const int co = g & 1023, t = g >> 10;
  double m0 = C[((size_t)0*TPI + t)*1024 + co];
  double m1 = C[((size_t)1*TPI + t)*1024 + co];
  double m2 = C[((size_t)2*TPI + t)*1024 + co];
  double m3 = C[((size_t)3*TPI + t)*1024 + co];
  double m4 = C[((size_t)4*TPI + t)*1024 + co];
  double m5 = C[((size_t)5*TPI + t)*1024 + co];
  double s[4];
#pragma unroll
  for (int bb = 0; bb < 4; ++bb)
    s[bb] = ATd[bb][0]*m0 + ATd[bb][1]*m1 + ATd[bb][2]*m2
          + ATd[bb][3]*m3 + ATd[bb][4]*m4 + ATd[bb][5]*m5;
  const int ty = t / 21, tx = t % 21;
#pragma unroll
  for (int a = 0; a < 4; ++a) {
    const int y = ty*4 + a;
    if (y >= HH) continue;
    const double fa = ATd[a][r];
#pragma unroll
    for (int bb = 0; bb < 4; ++bb) {
      const size_t idx = ((size_t)(y*WW + tx*4 + bb))*1024 + co;
      if (r == 0) h64b[idx] = fa * s[bb];
      else        h64b[idx] += fa * s[bb];
    }
  }
}

// ================= W5: finalize h = relu(h64 + bias) -> NCHW f32 (64x64 LDS transpose) =================
__launch_bounds__(256)
__global__ void fin_k(const double* __restrict__ h64, const float* __restrict__ bias,
                      float* __restrict__ h) {
  __shared__ float T[64*65];
  const int m0  = blockIdx.x * 64;     // 66 m-tiles
  const int co0 = blockIdx.y * 64;     // 16 co-groups
  const int b   = blockIdx.z;
  const int tid = threadIdx.x;
#pragma unroll
  for (int i = 0; i < 16; ++i) {
    int e = tid + i*256;
    int mi = e >> 6, coi = e & 63;
    int m = m0 + mi;
    double v = 0.0;
    if (m < HWX) v = h64[((size_t)b*HWX + m)*1024 + co0 + coi];
    T[mi*65 + coi] = (float)fmax(v + (double)bias[co0 + coi], 0.0);
  }
  __syncthreads();
#pragma unroll
  for (int i = 0; i < 16; ++i) {
    int e = tid + i*256;
    int coi = e >> 6, mi = e & 63;
    int m = m0 + mi;
    if (m < HWX) h[((size_t)(b*COUT + co0 + coi))*HWX + m] = T[mi*65 + coi];
  }
}

// ================= K2a: transpose head weights to [c][96] =================
__global__ void wt_k(const float* __restrict__ cls_w, const float* __restrict__ bbox_w,
                     float* __restrict__ wT) {
  int t = blockIdx.x*256 + threadIdx.x;
  if (t >= 96*1024) return;
  int c = t / 96, o = t - (t/96)*96;
  float v = 0.f;
  if (o < 30)      v = cls_w[(size_t)o*1024 + c];
  else if (o < 90) v = bbox_w[(size_t)(o-30)*1024 + c];
  wT[t] = v;
}

// ================= K2: heads as fp64 MFMA GEMM, M=32 tile, 264 blocks =================
__launch_bounds__(256, 2)
__global__ void heads_k(const float* __restrict__ h, const float* __restrict__ wT,
                        const float* __restrict__ cls_b, const float* __restrict__ bbox_b,
                        float* __restrict__ out_cls, float* __restrict__ out_bbox) {
  __shared__ __align__(16) float As[2][32*32];   // 2 x 4 KB  [k][m]
  __shared__ __align__(16) float Bs[2][32*96];   // 2 x 12 KB [k][o]
  const int tid = threadIdx.x;
  const int lane = tid & 63;
  const int w = tid >> 6;
  const int wm = w >> 1, wn = w & 1;     // wave: 16m x 48o
  const int l15 = lane & 15, lq = lane >> 4;
  const int mt = blockIdx.x, b = blockIdx.y;
  const int m0 = mt * 32;

  // ---- layout-proof D probe ----
  int pidx[4], nidx[4];
  {
    dx4 pr = {0.,0.,0.,0.}, pc = {0.,0.,0.,0.};
    pr = MFMA64((double)l15, 1.0, pr);
    pc = MFMA64(1.0, (double)l15, pc);
#pragma unroll
    for (int i = 0; i < 4; ++i) {
      pidx[i] = ((int)pr[i]) >> 2;
      nidx[i] = ((int)pc[i]) >> 2;
    }
  }

  auto stage = [&](int c0, int slot) {
    {
      int row = tid >> 3, cp = tid & 7;
      int mm = m0 + cp*4; if (mm > HWX - 4) mm = HWX - 4;   // 4196, 16B-aligned
      gload16(h + ((size_t)(b*COUT + c0 + row))*HWX + mm,
              (char*)&As[slot][0] + tid*16);
    }
#pragma unroll
    for (int i = 0; i < 3; ++i) {
      int e = tid + i*256;
      int row = e / 24, q = e % 24;
      gload16(wT + (size_t)(c0 + row)*96 + q*4,
              (char*)&Bs[slot][0] + e*16);
    }
  };

  dx4 acc[3];
#pragma unroll
  for (int j = 0; j < 3; ++j) acc[j] = (dx4){0.,0.,0.,0.};

  stage(0, 0);
  __syncthreads();
  int cur = 0;
#pragma unroll 1
  for (int c0 = 0; c0 < CIN; c0 += 32) {
    if (c0 + 32 < CIN) stage(c0 + 32, cur ^ 1);
    const float* Ap = &As[cur][0];
    const float* Bp = &Bs[cur][0];
#pragma unroll
    for (int kk = 0; kk < 32; kk += 4) {
      double a0 = (double)Ap[(kk + lq)*32 + wm*16 + l15];
      const int bb = (kk + lq)*96 + wn*48 + l15;
      double b0 = (double)Bp[bb];
      double b1 = (double)Bp[bb + 16];
      double b2 = (double)Bp[bb + 32];
      acc[0] = MFMA64(a0, b0, acc[0]);
      acc[1] = MFMA64(a0, b1, acc[1]);
      acc[2] = MFMA64(a0, b2, acc[2]);
    }
    __syncthreads();
    cur ^= 1;
  }

#pragma unroll
  for (int nf = 0; nf < 3; ++nf) {
#pragma unroll
    for (int i = 0; i < 4; ++i) {
      int m = m0 + wm*16 + pidx[i];
      int o = wn*48 + nf*16 + nidx[i];
      if (m < HWX) {
        if (o < 30) {
          out_cls[((size_t)(b*30 + o))*HWX + m] =
              (float)(acc[nf][i] + (double)cls_b[o]);
        } else if (o < 90) {
          out_bbox[((size_t)(b*60 + (o - 30)))*HWX + m] =
              (float)(acc[nf][i] + (double)bbox_b[o - 30]);
        }
      }
    }
  }
}

// ================= K2b: scores = sigmoid(l1-l0), fp64 interior =================
__global__ void score_k(const float* __restrict__ out_cls, float* __restrict__ scores) {
  int t = blockIdx.x*256 + threadIdx.x;
  if (t >= BATCH*NSC) return;
  int b = t / NSC; int r = t - b*NSC;
  int m = r / NA;  int a = r - m*NA;
  float l0 = out_cls[((size_t)(b*30 + a))*HWX + m];
  float l1 = out_cls[((size_t)(b*30 + a + NA))*HWX + m];
  double p = 1.0 / (1.0 + exp((double)l0 - (double)l1));
  scores[t] = (float)p;
}

// ================= K3: parallel top-2000 pipeline =================
// Selection semantics identical to the R6-passing kernel: 16-bit radix cut,
// candidates = superset of top-2000, ordered desc by unique key (score_bits, ~idx).
// R18: sortk_k (8192 bitonic, 2 blocks, 91 barrier passes, 117us) replaced by
// rank_k: keys are globally UNIQUE -> rank(key)=#{keys>key} is a bijection onto
// [0,count); emitting at top_idx[rank] reproduces the descending sort exactly,
// with zero cross-thread deps (32x2 blocks, LDS-broadcast scans, ~2050 iters).

// T0: zero topk scratch (hists/cuts/cnt only — gkeys needs no zeroing)
__global__ void tz_k(unsigned* __restrict__ gz) {
  int t = blockIdx.x*256 + threadIdx.x;
  if (t < TZ_WORDS) gz[t] = 0u;
}

// T1: per-block LDS hist of bits 24-31 -> global merge
__launch_bounds__(256)
__global__ void histA_k(const float* __restrict__ scores, unsigned* __restrict__ ghist) {
  __shared__ unsigned lh[256];
  const int b = blockIdx.y;
  const int base = blockIdx.x * 1024;
  lh[threadIdx.x] = 0;
  __syncthreads();
  const float* sc = scores + (size_t)b*NSC;
#pragma unroll
  for (int q = 0; q < 4; ++q) {
    int i = base + threadIdx.x + q*256;
    if (i < NSC) atomicAdd(&lh[__float_as_uint(sc[i]) >> 24], 1u);
  }
  __syncthreads();
  unsigned v = lh[threadIdx.x];
  if (v) atomicAdd(&ghist[b*256 + threadIdx.x], v);
}

// T2: cut A via parallel suffix-scan (no serial 256-load chain)
__launch_bounds__(256)
__global__ void cutA_k(const unsigned* __restrict__ ghist, unsigned* __restrict__ gcutA) {
  __shared__ unsigned s[256];
  const int b = blockIdx.x;
  const int t = threadIdx.x;
  s[t] = ghist[b*256 + t];
  __syncthreads();
  for (int off = 1; off < 256; off <<= 1) {
    unsigned v = (t + off < 256) ? s[t + off] : 0u;
    __syncthreads();
    s[t] += v;
    __syncthreads();
  }
  unsigned cum  = s[t];                       // sum_{j>=t} hist[j]
  unsigned cum1 = (t < 255) ? s[t + 1] : 0u;
  if (cum >= TOPN && (t == 255 || cum1 < TOPN))
    gcutA[b] = ((unsigned)t << 16) | (TOPN - cum1);    // b1 | need
}

// T3: hist of bits 16-23 within top-byte bin b1
__launch_bounds__(256)
__global__ void histB_k(const float* __restrict__ scores, const unsigned* __restrict__ gcutA,
                        unsigned* __restrict__ ghist2) {
  __shared__ unsigned lh[256];
  const int b = blockIdx.y;
  const unsigned b1 = gcutA[b] >> 16;
  const int base = blockIdx.x * 1024;
  lh[threadIdx.x] = 0;
  __syncthreads();
  const float* sc = scores + (size_t)b*NSC;
#pragma unroll
  for (int q = 0; q < 4; ++q) {
    int i = base + threadIdx.x + q*256;
    if (i < NSC) {
      unsigned k = __float_as_uint(sc[i]);
      if ((k >> 24) == b1) atomicAdd(&lh[(k >> 16) & 255u], 1u);
    }
  }
  __syncthreads();
  unsigned v = lh[threadIdx.x];
  if (v) atomicAdd(&ghist2[b*256 + threadIdx.x], v);
}

// T4: cut B -> 16-bit cut
__launch_bounds__(256)
__global__ void cutB_k(const unsigned* __restrict__ ghist2, const unsigned* __restrict__ gcutA,
                       unsigned* __restrict__ gcutB) {
  __shared__ unsigned s[256];
  const int b = blockIdx.x;
  const int t = threadIdx.x;
  const unsigned b1 = gcutA[b] >> 16, need = gcutA[b] & 0xFFFFu;
  s[t] = ghist2[b*256 + t];
  __syncthreads();
  for (int off = 1; off < 256; off <<= 1) {
    unsigned v = (t + off < 256) ? s[t + off] : 0u;
    __syncthreads();
    s[t] += v;
    __syncthreads();
  }
  unsigned cum  = s[t];
  unsigned cum1 = (t < 255) ? s[t + 1] : 0u;
  if (cum >= need && (t == 255 || cum1 < need))
    gcutB[b] = (b1 << 8) | (unsigned)t;                // cut16
}

// T5: compact candidates (wave-aggregated global append; order irrelevant)
__launch_bounds__(256)
__global__ void compact_k(const float* __restrict__ scores, const unsigned* __restrict__ gcutB,
                          unsigned long long* __restrict__ gkeys, unsigned* __restrict__ gcnt) {
  const int b = blockIdx.y;
  const unsigned cut = gcutB[b];
  const int base = blockIdx.x * 1024;
  const int lane = threadIdx.x & 63;
  const float* sc = scores + (size_t)b*NSC;
#pragma unroll
  for (int q = 0; q < 4; ++q) {
    int i = base + threadIdx.x + q*256;
    bool pred = false; unsigned k = 0u;
    if (i < NSC) { k = __float_as_uint(sc[i]); pred = ((k >> 16) >= cut); }
    unsigned long long m = __ballot(pred);
    if (m) {
      int leader = __ffsll((long long)m) - 1;
      unsigned bp = 0;
      if (lane == leader) bp = atomicAdd(&gcnt[b], (unsigned)__popcll(m));
      bp = __shfl(bp, leader);
      if (pred) {
        unsigned p = bp + (unsigned)__popcll(m & ((1ull << lane) - 1ull));
        if (p < CAPG)
          gkeys[(size_t)b*CAPG + p] =
              ((unsigned long long)k << 32) | (unsigned long long)(0xFFFFFFFFu - (unsigned)i);
      }
    }
  }
}

// T6: rank-select emit (replaces bitonic sort)
#define RCH 2048   // keys per LDS chunk (16 KB)
__launch_bounds__(256)
__global__ void rank_k(const unsigned long long* __restrict__ gkeys,
                       const unsigned* __restrict__ gcnt,
                       unsigned* __restrict__ top_idx, float* __restrict__ top_score) {
  __shared__ unsigned long long ks[RCH];
  const int b = blockIdx.y;
  int count = (int)gcnt[b]; if (count > CAPG) count = CAPG;
  if (blockIdx.x * 256 >= count) return;        // uniform whole-block exit
  const unsigned long long* kb = gkeys + (size_t)b*CAPG;
  const int cand = blockIdx.x*256 + threadIdx.x;
  const bool act = (cand < count);
  const unsigned long long mykey = act ? kb[cand] : 0ull;
  int rank = 0;
#pragma unroll 1
  for (int c0 = 0; c0 < count; c0 += RCH) {
    const int lim = (count - c0 < RCH) ? (count - c0) : RCH;
    __syncthreads();
    for (int j = threadIdx.x; j < lim; j += 256) ks[j] = kb[c0 + j];
    __syncthreads();
    if (act) {
#pragma unroll 4
      for (int j = 0; j < lim; ++j) rank += (ks[j] > mykey) ? 1 : 0;
    }
  }
  if (act && rank < TOPN) {
    top_idx[(size_t)b*TOPN + rank]   = 0xFFFFFFFFu - (unsigned)(mykey & 0xFFFFFFFFull);
    top_score[(size_t)b*TOPN + rank] = __uint_as_float((unsigned)(mykey >> 32));
  }
}

// ================= K4: decode + clip top boxes (fp64) =================
__global__ void decode_k(const unsigned* __restrict__ top_idx,
                         const float* __restrict__ out_bbox,
                         const float* __restrict__ im_info,
                         double* __restrict__ boxesd) {
  int t = blockIdx.x*256 + threadIdx.x;
  if (t >= BATCH*TOPN) return;
  int b = t / TOPN;
  unsigned idx = top_idx[t];
  int a = idx % NA; int m = idx / NA;
  int yy = m / WW;  int xx = m - yy*WW;
  double sx = (double)xx * 16.0, sy = (double)yy * 16.0;
  double A0 = ANCH[a][0] + sx, A1 = ANCH[a][1] + sy;
  double A2 = ANCH[a][2] + sx, A3 = ANCH[a][3] + sy;
  double w_ = A2 - A0 + 1.0, h_ = A3 - A1 + 1.0;
  double cx = A0 + 0.5*w_,  cy = A1 + 0.5*h_;
  const float* bp = out_bbox + (size_t)b*60*HWX;
  double dx = (double)bp[(a*4+0)*HWX + m];
  double dy = (double)bp[(a*4+1)*HWX + m];
  double dw = fmin((double)bp[(a*4+2)*HWX + m], BBOX_CLIP);
  double dh = fmin((double)bp[(a*4+3)*HWX + m], BBOX_CLIP);
  double pcx = dx*w_ + cx, pcy = dy*h_ + cy;
  double pw = exp(dw)*w_,  ph = exp(dh)*h_;
  double x1 = pcx - 0.5*pw, y1 = pcy - 0.5*ph;
  double x2 = pcx + 0.5*pw - 1.0, y2 = pcy + 0.5*ph - 1.0;
  double hmax = (double)im_info[b*3+0] - 1.0;
  double wmax = (double)im_info[b*3+1] - 1.0;
  x1 = fmin(fmax(x1, 0.0), wmax); x2 = fmin(fmax(x2, 0.0), wmax);
  y1 = fmin(fmax(y1, 0.0), hmax); y2 = fmin(fmax(y2, 0.0), hmax);
  boxesd[(size_t)t*4+0] = x1; boxesd[(size_t)t*4+1] = y1;
  boxesd[(size_t)t*4+2] = x2; boxesd[(size_t)t*4+3] = y2;
}

// ================= K5: IoU suppression bitmask, FULL symmetric rows =================
__launch_bounds__(256)
__global__ void iou_k(const double* __restrict__ boxesd,
                      unsigned long long* __restrict__ mask) {
  __shared__ double BX[TOPN*4];    // 64 KB
  const int b  = blockIdx.y;
  const int i0 = blockIdx.x * 8;
  const double* src = boxesd + (size_t)b*TOPN*4;
  for (int e = threadIdx.x; e < TOPN*4; e += 256) BX[e] = src[e];
  __syncthreads();
  const int il = threadIdx.x >> 5;
  const int w  = threadIdx.x & 31;
  const int i  = i0 + il;
  double x1 = BX[i*4+0], y1 = BX[i*4+1], x2 = BX[i*4+2], y2 = BX[i*4+3];
  double ai = (x2 - x1 + 1.0)*(y2 - y1 + 1.0);
  unsigned long long bits = 0ull;
  for (int jj = 0; jj < 64; ++jj) {
    int j = w*64 + jj;
    if (j >= TOPN) break;
    double bx1 = BX[j*4+0], by1 = BX[j*4+1], bx2 = BX[j*4+2], by2 = BX[j*4+3];
    double xx1 = fmax(x1, bx1), yy1 = fmax(y1, by1);
    double xx2 = fmin(x2, bx2), yy2 = fmin(y2, by2);
    double iw = fmax(xx2 - xx1 + 1.0, 0.0);
    double ih = fmax(yy2 - yy1 + 1.0, 0.0);
    double inter = iw * ih;
    double aj = (bx2 - bx1 + 1.0)*(by2 - by1 + 1.0);
    double iou = inter / (ai + aj - inter);
    if (iou > 0.7) bits |= (1ull << jj);
  }
  mask[((size_t)b*TOPN + i)*32 + w] = bits;
}

// ================= K6: NMS scan — register bitmask + early exit at 300 kept =================
__launch_bounds__(256)
__global__ void nms_out_k(const unsigned long long* __restrict__ mask,
                          const double* __restrict__ boxesd,
                          const float* __restrict__ top_score,
                          float* __restrict__ rois, float* __restrict__ probs) {
  __shared__ unsigned long long MS[256*32];  // 64 KB chunk of mask rows
  __shared__ int kept_idx[POSTN];
  __shared__ int s_cnt, s_done;
  const int b = blockIdx.x;
  const int tid = threadIdx.x;
  if (tid == 0) { s_done = 0; s_cnt = 0; }

  unsigned long long rem = 0ull;     // lane L<32: suppression bits 64L..64L+63
  int cnt = 0;
  const int L = tid;                 // lane id within wave 0 (tid<64)

  for (int ch = 0; ch < 8; ++ch) {
    __syncthreads();
    if (s_done) break;
    const int base = ch * 256;
    for (int e = tid; e < 256*32; e += 256) {
      int row = base + (e >> 5);
      MS[e] = (row < TOPN) ? mask[((size_t)b*TOPN + row)*32 + (e & 31)] : 0ull;
    }
    __syncthreads();
    if (tid < 64) {
      const int lim = (base + 256 < TOPN) ? base + 256 : TOPN;
      int pos = base;
      while (true) {
        unsigned long long wmask = ~rem;
        int lo = pos - 64*L;
        if (lo >= 64) wmask = 0ull;
        else if (lo > 0) wmask &= (~0ull) << lo;
        int hi = lim - 64*L;
        if (hi <= 0) wmask = 0ull;
        else if (hi < 64) wmask &= ((1ull << hi) - 1ull);
        if (L >= 32) wmask = 0ull;
        unsigned long long bal = __ballot(wmask != 0ull);
        if (bal == 0ull) break;
        int lstar = __ffsll((long long)bal) - 1;
        int cand = 64*L + (wmask ? (__ffsll((long long)wmask) - 1) : 0);
        int i = __shfl(cand, lstar);
        if (L == 0) kept_idx[cnt] = i;
        ++cnt;
        if (cnt >= POSTN) {
          if (L == 0) { s_done = 1; }
          break;
        }
        if (L < 32) rem |= MS[(i - base)*32 + L];
        pos = i + 1;
      }
      if (L == 0) s_cnt = cnt;
    }
  }
  __syncthreads();
  const int n = s_cnt;

  // zero-init all rows (coords + probs), batch id column
  for (int j = tid; j < POSTN; j += 256) {
    float* rr = rois + ((size_t)b*POSTN + j)*5;
    rr[0] = (float)b; rr[1] = 0.f; rr[2] = 0.f; rr[3] = 0.f; rr[4] = 0.f;
    probs[(size_t)b*POSTN + j] = 0.f;
  }
  // emit kept boxes in index order (same thread owns row j in both loops)
  for (int j = tid; j < n; j += 256) {
    int i = kept_idx[j];
    const double* bx = boxesd + ((size_t)b*TOPN + i)*4;
    float* rr = rois + ((size_t)b*POSTN + j)*5;
    rr[1] = (float)bx[0]; rr[2] = (float)bx[1];
    rr[3] = (float)bx[2]; rr[4] = (float)bx[3];
    probs[(size_t)b*POSTN + j] = top_score[(size_t)b*TOPN + i];
  }
}

// ================= launch =================
extern "C" void kernel_launch(void* const* d_in, const int* in_sizes, int n_in,
                              void* d_out, int out_size, void* d_ws, size_t ws_size,
                              hipStream_t stream) {
  const float* x      = (const float*)d_in[0];
  const float* conv_w = (const float*)d_in[1];
  const float* conv_b = (const float*)d_in[2];
  const float* cls_w  = (const float*)d_in[3];
  const float* cls_b  = (const float*)d_in[4];
  const float* bbox_w = (const float*)d_in[5];
  const float* bbox_b = (const float*)d_in[6];
  const float* im_info= (const float*)d_in[7];

  float* out  = (float*)d_out;
  float* out_cls  = out + CLS_OFF;
  float* out_bbox = out + BBOX_OFF;
  float* rois     = out + ROIS_OFF;
  float* probs    = out + PROBS_OFF;

  float* wsf = (float*)d_ws;
  float*    wT      = wsf + WS_WT;
  double*   U       = (double*)(wsf + WS_U);
  double*   V       = (double*)(wsf + WS_V);
  double*   Cws     = (double*)(wsf + WS_C);
  double*   h64     = (double*)(wsf + WS_H64);
  // overlays
  float*    h       = wsf + OV_H;      // over V (dead after last wgemm)
  float*    scores  = wsf + OV_SC;     // over C (dead after last otrans)
  unsigned* top_idx = (unsigned*)(wsf + OV_TIDX);
  float*    top_sc  = wsf + OV_TSC;
  double*   boxesd  = (double*)(wsf + OV_BOX);
  unsigned long long* mask = (unsigned long long*)(wsf + OV_MASK);
  unsigned* ghist   = (unsigned*)(wsf + OV_GH);
  unsigned* ghist2  = (unsigned*)(wsf + OV_GH2);
  unsigned* gcutA   = (unsigned*)(wsf + OV_GCA);
  unsigned* gcutB   = (unsigned*)(wsf + OV_GCB);
  unsigned* gcnt    = (unsigned*)(wsf + OV_GCN);
  unsigned long long* gkeys = (unsigned long long*)(wsf + OV_GK);

  wt_k<<<dim3((96*1024 + 255)/256), dim3(256), 0, stream>>>(cls_w, bbox_w, wT);
  for (int r = 0; r < 6; ++r) {
    wtrans_k<<<dim3(4096), dim3(256), 0, stream>>>(conv_w, V, r);   // b-independent: once per r
    for (int b = 0; b < 2; ++b) {
      itrans_k<<<dim3(1664), dim3(256), 0, stream>>>(x, U, b, r);
      wgemm_k<<<dim3(80, 1, 6), dim3(256), 0, stream>>>(U, V, Cws);
      otrans_k<<<dim3(1092), dim3(256), 0, stream>>>(Cws, h64 + (size_t)b*HWX*1024, r);
    }
  }
  fin_k<<<dim3(66, 16, 2), dim3(256), 0, stream>>>(h64, conv_b, h);
  heads_k<<<dim3(132, 2), dim3(256), 0, stream>>>(h, wT, cls_b, bbox_b, out_cls, out_bbox);
  tz_k<<<dim3((TZ_WORDS + 255)/256), dim3(256), 0, stream>>>(ghist);
  score_k<<<dim3((BATCH*NSC + 255)/256), dim3(256), 0, stream>>>(out_cls, scores);
  histA_k<<<dim3(62, 2), dim3(256), 0, stream>>>(scores, ghist);
  cutA_k<<<dim3(2), dim3(256), 0, stream>>>(ghist, gcutA);
  histB_k<<<dim3(62, 2), dim3(256), 0, stream>>>(scores, gcutA, ghist2);
  cutB_k<<<dim3(2), dim3(256), 0, stream>>>(ghist2, gcutA, gcutB);
  compact_k<<<dim3(62, 2), dim3(256), 0, stream>>>(scores, gcutB, gkeys, gcnt);
  rank_k<<<dim3(CAPG/256, 2), dim3(256), 0, stream>>>(gkeys, gcnt, top_idx, top_sc);
  decode_k<<<dim3((BATCH*TOPN + 255)/256), dim3(256), 0, stream>>>(top_idx, out_bbox, im_info, boxesd);
  iou_k<<<dim3(TOPN/8, 2), dim3(256), 0, stream>>>(boxesd, mask);
  nms_out_k<<<dim3(2), dim3(256), 0, stream>>>(mask, boxesd, top_sc, rois, probs);
}